// Round 12
// baseline (2180.733 us; speedup 1.0000x reference)
//
#include <hip/hip_runtime.h>

#define BB 8
#define NN 2048
#define DD 64
#define NC 4            // split-K chunks for out_gemm
#define NSWEEP 19       // u1 + 9x(v,u); final v10 fused into out_gemm
#define CROWS 16        // rows per coop block
#define CPB   (NN / CROWS)   // coop blocks per batch = 128
constexpr float EPS = 0.1f;
constexpr float KSCALE = 4096.0f;   // off-diag fp8 scale; diag handled analytically

typedef short bf16x8 __attribute__((ext_vector_type(8)));
typedef float f32x16 __attribute__((ext_vector_type(16)));
typedef float f32x2  __attribute__((ext_vector_type(2)));

// ---------------------------------------------------------------- fp8 helpers
__device__ inline float e4m3_to_f32_manual(unsigned int b) {
    unsigned int e = (b >> 3) & 15u, m = b & 7u;
    float v;
    if (e == 0) v = (float)m * 0.001953125f;              // m * 2^-9
    else        v = __uint_as_float(((e + 120u) << 23) | (m << 20));
    return (b & 0x80u) ? -v : v;
}

template <bool HI>
__device__ inline f32x2 cvt2_fp8(unsigned int w) {
#if __has_builtin(__builtin_amdgcn_cvt_pk_f32_fp8)
    return __builtin_amdgcn_cvt_pk_f32_fp8(w, HI);
#else
    f32x2 r; unsigned int s = HI ? (w >> 16) : w;
    r[0] = e4m3_to_f32_manual(s & 255u);
    r[1] = e4m3_to_f32_manual((s >> 8) & 255u);
    return r;
#endif
}

__device__ inline unsigned char f32_to_e4m3(float f) {   // f in [0, 448]
#if __has_builtin(__builtin_amdgcn_cvt_pk_fp8_f32)
    return (unsigned char)(__builtin_amdgcn_cvt_pk_fp8_f32(f, f, 0, false) & 0xFF);
#else
    if (!(f > 0.f)) return 0;
    if (f >= 448.f) return 0x7E;
    int e; float m = frexpf(f, &e);            // f = m*2^e, m in [0.5,1)
    if (e >= -5) {                              // normal: f >= 2^-6
        int mant = (int)roundf(m * 16.f) - 8;   // 0..8
        int ef = e + 6;
        if (mant == 8) { mant = 0; ef += 1; }
        if (ef >= 16) return 0x7E;
        return (unsigned char)((ef << 3) | mant);
    }
    int mant = (int)roundf(f * 512.f);          // subnormal
    if (mant >= 8) return 0x08;
    return (unsigned char)mant;
#endif
}

__device__ inline unsigned int pack4_e4m3(float a, float b, float c, float d) {
#if __has_builtin(__builtin_amdgcn_cvt_pk_fp8_f32)
    unsigned int w = 0;
    w = (unsigned int)__builtin_amdgcn_cvt_pk_fp8_f32(a, b, (int)w, false);
    w = (unsigned int)__builtin_amdgcn_cvt_pk_fp8_f32(c, d, (int)w, true);
    return w;
#else
    return (unsigned int)f32_to_e4m3(a) | ((unsigned int)f32_to_e4m3(b) << 8)
         | ((unsigned int)f32_to_e4m3(c) << 16) | ((unsigned int)f32_to_e4m3(d) << 24);
#endif
}

__device__ inline unsigned short f2bf_rne(float f) {
    unsigned int u = __float_as_uint(f);
    u += 0x7FFFu + ((u >> 16) & 1u);
    return (unsigned short)(u >> 16);
}

// ---------------------------------------------------------------- stats1
__global__ __launch_bounds__(256) void stats1(const float* __restrict__ X,
                                              unsigned short* __restrict__ Xbf,
                                              float* __restrict__ sq,
                                              float* __restrict__ pcol,
                                              float* __restrict__ ptot,
                                              float* __restrict__ outW) {
    const int blk = blockIdx.x;          // 0 .. BB*32-1
    const int b   = blk & 7;
    const int ch  = blk >> 3;            // 0..31
    const int r0  = ch * 64;
    const int t = threadIdx.x, w = t >> 6, lane = t & 63;
    const int gidx = blk * 256 + t;
    if (gidx < BB * NN) outW[gidx] = 1.0f / (float)NN;
    const float* Xb = X + (size_t)b * NN * DD;
    unsigned short* Xbfb = Xbf + (size_t)b * NN * DD;
    float cs = 0.f, sqtot = 0.f;
    #pragma unroll
    for (int i = w; i < 64; i += 4) {
        const int row = r0 + i;
        float x = Xb[(size_t)row * DD + lane];
        unsigned short hb = f2bf_rne(x);
        Xbfb[(size_t)row * DD + lane] = hb;
        float xr = __uint_as_float((unsigned int)hb << 16);
        cs += xr;
        float s = xr * xr;
        #pragma unroll
        for (int off = 32; off > 0; off >>= 1) s += __shfl_down(s, off);
        if (lane == 0) { sq[b * NN + row] = s; sqtot += s; }
    }
    __shared__ float colS[4][64];
    __shared__ float totS[4];
    colS[w][lane] = cs;
    if (lane == 0) totS[w] = sqtot;
    __syncthreads();
    if (t < 64)
        pcol[(b * 32 + ch) * 64 + t] = colS[0][t] + colS[1][t] + colS[2][t] + colS[3][t];
    if (t == 0)
        ptot[b * 32 + ch] = totS[0] + totS[1] + totS[2] + totS[3];
}

// ---------------------------------------------------------------- stats2
__global__ void stats2(const float* __restrict__ pcol,
                       const float* __restrict__ ptot,
                       float* __restrict__ scale) {
    const int b = blockIdx.x, t = threadIdx.x;   // 64 threads
    float c = 0.f;
    #pragma unroll
    for (int p = 0; p < 32; ++p) c += pcol[(b * 32 + p) * 64 + t];
    float s2 = c * c;
    #pragma unroll
    for (int off = 32; off > 0; off >>= 1) s2 += __shfl_down(s2, off);
    if (t == 0) {
        float T = 0.f;
        #pragma unroll
        for (int p = 0; p < 32; ++p) T += ptot[b * 32 + p];
        float cmean = 2.0f * T / (float)NN
                    - 2.0f * s2 / ((float)NN * (float)NN) + 1e-8f;
        scale[b] = -1.0f / (cmean * EPS);
    }
}

// ---------------------------------------------------------------- build_K
// SYMMETRIC: one block per unordered tile pair (I<=J) per batch (528*8 blocks).
__global__ __launch_bounds__(256) void build_K(const unsigned short* __restrict__ Xbf,
                                               const float* __restrict__ sq,
                                               const float* __restrict__ scale,
                                               unsigned char* __restrict__ K) {
    __shared__ float T[64][68];
    const int bid = blockIdx.x;                   // 0..4223
    const int b = bid & 7;
    int q = bid >> 3, I = 0;                      // triangular decode (uniform)
    while (q >= 32 - I) { q -= 32 - I; ++I; }
    const int J = I + q;                          // I <= J
    const int t = threadIdx.x, w = t >> 6;
    const int lane = t & 63, l31 = lane & 31, lh = lane >> 5;
    const int wr = w >> 1, wc = w & 1;            // 32x32 quadrant of 64x64 tile
    const unsigned short* Xb = Xbf + (size_t)b * NN * DD;
    const int n_row = I * 64 + wr * 32 + l31;     // A: lane holds row l31 (I side)
    const int m_row = J * 64 + wc * 32 + l31;     // B: lane holds col l31 (J side)
    bf16x8 af[4], bf[4];
    #pragma unroll
    for (int s = 0; s < 4; ++s) {                 // k = s*16 + lh*8 + (0..7)
        af[s] = *(const bf16x8*)(Xb + (size_t)n_row * DD + s * 16 + lh * 8);
        bf[s] = *(const bf16x8*)(Xb + (size_t)m_row * DD + s * 16 + lh * 8);
    }
    f32x16 acc = {};
    #pragma unroll
    for (int s = 0; s < 4; ++s)
        acc = __builtin_amdgcn_mfma_f32_32x32x16_bf16(af[s], bf[s], acc, 0, 0, 0);
    // C/D: col = l31, row = (r&3) + 8*(r>>2) + 4*lh   [m74/m101 verified]
    const float sc = scale[b];
    const float* sqb = sq + b * NN;
    const int gm = J * 64 + wc * 32 + l31;
    const float sqm = sqb[gm];
    #pragma unroll
    for (int r = 0; r < 16; ++r) {
        const int row = (r & 3) + 8 * (r >> 2) + 4 * lh;
        const int gn = I * 64 + wr * 32 + row;
        float val = KSCALE * __expf(sc * (sqb[gn] + sqm - 2.0f * acc[r]));
        T[wr * 32 + row][wc * 32 + l31] = (gn == gm) ? 0.0f : val;
    }
    __syncthreads();
    unsigned char* Kb = K + (size_t)b * NN * NN;
    // ---- store 1: K[I-rows][J-cols], row-major from LDS
    {
        const int orow = t >> 2, oseg = t & 3;    // 64 rows x 4 segs of 16
        float vv[16];
        #pragma unroll
        for (int j = 0; j < 4; ++j)
            *(float4*)&vv[j * 4] = *(const float4*)&T[orow][oseg * 16 + j * 4];
        uint4 o;
        o.x = pack4_e4m3(vv[0],  vv[1],  vv[2],  vv[3]);
        o.y = pack4_e4m3(vv[4],  vv[5],  vv[6],  vv[7]);
        o.z = pack4_e4m3(vv[8],  vv[9],  vv[10], vv[11]);
        o.w = pack4_e4m3(vv[12], vv[13], vv[14], vv[15]);
        *(uint4*)(Kb + (size_t)(I * 64 + orow) * NN + J * 64 + oseg * 16) = o;
    }
    // ---- store 2 (I<J only): transpose tile -> K[J-rows][I-cols]
    if (I != J) {
        const int c = t >> 2, rseg = t & 3;       // 64 cols x 4 segs of 16 rows
        float vv[16];
        #pragma unroll
        for (int j = 0; j < 16; ++j) vv[j] = T[rseg * 16 + j][c];
        uint4 o;
        o.x = pack4_e4m3(vv[0],  vv[1],  vv[2],  vv[3]);
        o.y = pack4_e4m3(vv[4],  vv[5],  vv[6],  vv[7]);
        o.z = pack4_e4m3(vv[8],  vv[9],  vv[10], vv[11]);
        o.w = pack4_e4m3(vv[12], vv[13], vv[14], vv[15]);
        *(uint4*)(Kb + (size_t)(J * 64 + c) * NN + I * 64 + rseg * 16) = o;
    }
}

// ---------------------------------------------------------------- zero_ctr
__global__ void zero_ctr(int* __restrict__ ctr) {
    ctr[threadIdx.x] = 0;
}

// ---------------------------------------------------------------- sink_all
// Persistent cooperative kernel: all 19 Sinkhorn half-sweeps in one launch.
// 1024 blocks (4/CU with 33KB LDS), block (b,j) owns CROWS=16 rows, cached
// in LDS once. Per-batch barrier between sweeps (device-scope, G16 pattern),
// with system-scope release/acquire + all-thread agent fence after.
__global__ __launch_bounds__(256, 4) void sink_all(const unsigned char* __restrict__ K,
                                                   const float* __restrict__ W,
                                                   float* u, float* v,
                                                   int* ctr) {
    __shared__ __align__(16) unsigned char Ks[CROWS * NN];   // 32 KB
    __shared__ float part[CROWS][4];
    __shared__ float numer[CROWS];
    const int bid = blockIdx.x;               // 0..1023
    const int b = bid & 7, j = bid >> 3;      // j 0..127
    const int r0 = j * CROWS;
    const int t = threadIdx.x, w = t >> 6, lane = t & 63;
    const unsigned char* Kb = K + ((size_t)b * NN + r0) * NN;
    #pragma unroll
    for (int i = 0; i < CROWS / 2; ++i) {     // 16B/thread x 8 iters = 32 KB
        const int f = t + i * 256;            // 0..2047
        const int row = f >> 7, off = (f & 127) * 16;
        *(uint4*)(Ks + row * NN + off) = *(const uint4*)(Kb + (size_t)row * NN + off);
    }
    if (t < CROWS) numer[t] = W[(size_t)b * NN + r0 + t] + 1e-16f;
    __syncthreads();
    const int c0 = w * 512 + lane * 8;        // this lane's column base
    #pragma unroll 1
    for (int s = 0; s < NSWEEP; ++s) {
        float vv[8];
        if (s == 0) {
            #pragma unroll
            for (int q = 0; q < 8; ++q) vv[q] = 1.0f;
        } else {
            const float* src = (s & 1) ? u : v;     // odd reads u, even reads v
            const float* sb = src + (size_t)b * NN + c0;
            *(float4*)&vv[0] = *(const float4*)sb;
            *(float4*)&vv[4] = *(const float4*)(sb + 4);
        }
        float p[CROWS];
        #pragma unroll
        for (int r = 0; r < CROWS; ++r) {
            const uint2 k8 = *(const uint2*)(Ks + r * NN + c0);
            f32x2 q0 = cvt2_fp8<false>(k8.x), q1 = cvt2_fp8<true>(k8.x);
            f32x2 q2 = cvt2_fp8<false>(k8.y), q3 = cvt2_fp8<true>(k8.y);
            p[r] = q0[0]*vv[0] + q0[1]*vv[1] + q1[0]*vv[2] + q1[1]*vv[3]
                 + q2[0]*vv[4] + q2[1]*vv[5] + q3[0]*vv[6] + q3[1]*vv[7];
        }
        #pragma unroll
        for (int off = 32; off > 0; off >>= 1)
            #pragma unroll
            for (int r = 0; r < CROWS; ++r) p[r] += __shfl_down(p[r], off);
        if (lane == 0)
            #pragma unroll
            for (int r = 0; r < CROWS; ++r) part[r][w] = p[r];
        __syncthreads();
        if (t < CROWS) {
            const int r = t;
            const float tot = part[r][0] + part[r][1] + part[r][2] + part[r][3];
            const float sv = (s == 0) ? 1.0f
                           : ((s & 1) ? u[(size_t)b * NN + r0 + r]
                                      : v[(size_t)b * NN + r0 + r]);
            const float num = (s & 1) ? (1.0f / (float)NN) : numer[r];
            float* dst = (s & 1) ? v : u;
            dst[(size_t)b * NN + r0 + r] = num / (tot + KSCALE * sv);
        }
        __syncthreads();
        if (t == 0) {
            __threadfence_system();           // release: writeback across XCDs
            atomicAdd(&ctr[b * NSWEEP + s], 1);
            while (__hip_atomic_load(&ctr[b * NSWEEP + s], __ATOMIC_ACQUIRE,
                                     __HIP_MEMORY_SCOPE_SYSTEM) < CPB) {}
        }
        __syncthreads();
        __threadfence();                      // all threads: invalidate stale L1/L2
    }
}

// ---------------------------------------------------------------- sink_pass
// Fallback path (non-cooperative). MODE 0: u-update; MODE 1: v-update;
// MODE 2: u-update with src == 1 (first sweep, replaces ucombine).
template <int MODE>
__global__ __launch_bounds__(256) void sink_pass(const unsigned char* __restrict__ K,
                                                 const float* __restrict__ vin,
                                                 const float* __restrict__ wts,
                                                 float* __restrict__ out) {
    __shared__ float vs[NN];
    const int bid = blockIdx.x;                   // 0..2047
    const int b = bid & 7, j = bid >> 3;          // j 0..255
    const int t = threadIdx.x, w = t >> 6, lane = t & 63;
    if (MODE == 2) {
        #pragma unroll
        for (int s = 0; s < 2; ++s) {
            float4 one = make_float4(1.f, 1.f, 1.f, 1.f);
            *(float4*)&vs[(t + s * 256) * 4] = one;
        }
    } else {
        const float* vb = vin + (size_t)b * NN;
        #pragma unroll
        for (int s = 0; s < 2; ++s)
            *(float4*)&vs[(t + s * 256) * 4] = *(const float4*)&vb[(t + s * 256) * 4];
    }
    __syncthreads();
    const int r0 = j * 8 + w * 2;                 // 2 rows per wave
    const unsigned char* Kr0 = K + ((size_t)b * NN + r0) * NN;
    const unsigned char* Kr1 = Kr0 + NN;
    float a0 = 0.f, a1 = 0.f;
    #pragma unroll
    for (int it = 0; it < 2; ++it) {
        const int m0 = it * 1024 + lane * 16;
        const uint4 ka = *(const uint4*)(Kr0 + m0);
        const uint4 kb = *(const uint4*)(Kr1 + m0);
        const float4 v0 = *(const float4*)&vs[m0];
        const float4 v1 = *(const float4*)&vs[m0 + 4];
        const float4 v2 = *(const float4*)&vs[m0 + 8];
        const float4 v3 = *(const float4*)&vs[m0 + 12];
        {
            f32x2 q0 = cvt2_fp8<false>(ka.x), q1 = cvt2_fp8<true>(ka.x);
            f32x2 q2 = cvt2_fp8<false>(ka.y), q3 = cvt2_fp8<true>(ka.y);
            f32x2 q4 = cvt2_fp8<false>(ka.z), q5 = cvt2_fp8<true>(ka.z);
            f32x2 q6 = cvt2_fp8<false>(ka.w), q7 = cvt2_fp8<true>(ka.w);
            a0 += q0[0]*v0.x + q0[1]*v0.y + q1[0]*v0.z + q1[1]*v0.w
                + q2[0]*v1.x + q2[1]*v1.y + q3[0]*v1.z + q3[1]*v1.w
                + q4[0]*v2.x + q4[1]*v2.y + q5[0]*v2.z + q5[1]*v2.w
                + q6[0]*v3.x + q6[1]*v3.y + q7[0]*v3.z + q7[1]*v3.w;
        }
        {
            f32x2 q0 = cvt2_fp8<false>(kb.x), q1 = cvt2_fp8<true>(kb.x);
            f32x2 q2 = cvt2_fp8<false>(kb.y), q3 = cvt2_fp8<true>(kb.y);
            f32x2 q4 = cvt2_fp8<false>(kb.z), q5 = cvt2_fp8<true>(kb.z);
            f32x2 q6 = cvt2_fp8<false>(kb.w), q7 = cvt2_fp8<true>(kb.w);
            a1 += q0[0]*v0.x + q0[1]*v0.y + q1[0]*v0.z + q1[1]*v0.w
                + q2[0]*v1.x + q2[1]*v1.y + q3[0]*v1.z + q3[1]*v1.w
                + q4[0]*v2.x + q4[1]*v2.y + q5[0]*v2.z + q5[1]*v2.w
                + q6[0]*v3.x + q6[1]*v3.y + q7[0]*v3.z + q7[1]*v3.w;
        }
    }
    #pragma unroll
    for (int off = 32; off > 0; off >>= 1) {
        a0 += __shfl_down(a0, off);
        a1 += __shfl_down(a1, off);
    }
    if (lane == 0) {
        const float n0 = (MODE == 1) ? (1.0f/(float)NN) : (wts[(size_t)b*NN + r0] + 1e-16f);
        const float n1 = (MODE == 1) ? (1.0f/(float)NN) : (wts[(size_t)b*NN + r0 + 1] + 1e-16f);
        out[(size_t)b * NN + r0]     = n0 / (a0 + KSCALE * vs[r0]);
        out[(size_t)b * NN + r0 + 1] = n1 / (a1 + KSCALE * vs[r0 + 1]);
    }
}

// ---------------------------------------------------------------- yprep
__global__ __launch_bounds__(256) void yprep(const float* __restrict__ X,
                                             const float* __restrict__ u,
                                             unsigned short* __restrict__ Yt) {
    __shared__ float T[64][65];
    const int bid = blockIdx.x;                   // 0..255
    const int b = bid & 7, nt = bid >> 3;
    const int t = threadIdx.x;
    const int nl = t >> 2, c0 = (t & 3) << 4;
    const float* Xb = X + ((size_t)b * NN + nt * 64) * DD;
    const float uu = u[(size_t)b * NN + nt * 64 + nl];
    #pragma unroll
    for (int j = 0; j < 4; ++j) {
        float4 x = *(const float4*)(Xb + (size_t)nl * DD + c0 + j * 4);
        T[c0 + j * 4 + 0][nl] = uu * x.x;
        T[c0 + j * 4 + 1][nl] = uu * x.y;
        T[c0 + j * 4 + 2][nl] = uu * x.z;
        T[c0 + j * 4 + 3][nl] = uu * x.w;
    }
    __syncthreads();
    const int d = t >> 2, n0 = (t & 3) << 4;
    unsigned short* Yr = Yt + ((size_t)b * DD + d) * NN + nt * 64 + n0;
    unsigned int ow[8];
    #pragma unroll
    for (int j = 0; j < 8; ++j) {
        unsigned int lo = f2bf_rne(T[d][n0 + 2 * j]);
        unsigned int hi = f2bf_rne(T[d][n0 + 2 * j + 1]);
        ow[j] = lo | (hi << 16);
    }
    *(uint4*)(Yr)     = make_uint4(ow[0], ow[1], ow[2], ow[3]);
    *(uint4*)(Yr + 8) = make_uint4(ow[4], ow[5], ow[6], ow[7]);
}

// ---------------------------------------------------------------- out_gemm
#define KP 136
#define YP 264
__global__ __launch_bounds__(256) void out_gemm(const unsigned char* __restrict__ K,
                                                const unsigned short* __restrict__ Yt,
                                                const float* __restrict__ u,
                                                float* __restrict__ pbuf,
                                                float* __restrict__ dpart) {
    __shared__ __align__(16) unsigned char KsB[64 * KP];
    __shared__ __align__(16) unsigned char YsB[64 * YP];
    const int bid = blockIdx.x;                   // 0..1023
    const int b = bid & 7, tix = bid >> 3;        // tix 0..127
    const int nc = tix & (NC - 1), mt = tix >> 2; // mt 0..31
    const int t = threadIdx.x, w = t >> 6, lane = t & 63;
    const int l31 = lane & 31, lh = lane >> 5;
    const int wr = w >> 1, wc = w & 1;
    const unsigned char*  Kb = K + (size_t)b * NN * NN + (size_t)(mt * 64) * NN;
    const unsigned short* Yb = Yt + (size_t)b * DD * NN;
    const float* ub = u + (size_t)b * NN;
    f32x16 acc = {};
    float ds = 0.f;
    for (int st = 0; st < (NN / NC) / 128; ++st) {
        const int n0 = nc * (NN / NC) + st * 128;
        __syncthreads();
        #pragma unroll
        for (int i = 0; i < 2; ++i) {             // K tile: 64 rows x 128 B
            const int f = t + i * 256;            // 0..511
            const int row = f >> 3, seg = (f & 7) * 16;
            *(uint4*)(KsB + row * KP + seg) =
                *(const uint4*)(Kb + (size_t)row * NN + n0 + seg);
        }
        #pragma unroll
        for (int i = 0; i < 4; ++i) {             // Y tile: 64 rows x 128 bf16
            const int f = t + i * 256;            // 0..1023
            const int row = f >> 4, sege = (f & 15) * 8;
            *(uint4*)(YsB + row * YP + sege * 2) =
                *(const uint4*)(Yb + (size_t)row * NN + n0 + sege);
        }
        __syncthreads();
        #pragma unroll
        for (int kk = 0; kk < 8; ++kk) {
            const uint2 k8 = *(const uint2*)(KsB + (wr * 32 + l31) * KP
                                             + kk * 16 + lh * 8);
            f32x2 p0 = cvt2_fp8<false>(k8.x);
            f32x2 p1 = cvt2_fp8<true>(k8.x);
            f32x2 p2 = cvt2_fp8<false>(k8.y);
            f32x2 p3 = cvt2_fp8<true>(k8.y);
            if (wc == 0) {
                const int nu = n0 + kk * 16 + lh * 8;
                const float4 ua = *(const float4*)(ub + nu);
                const float4 uc = *(const float4*)(ub + nu + 4);
                ds += p0[0]*ua.x + p0[1]*ua.y + p1[0]*ua.z + p1[1]*ua.w
                    + p2[0]*uc.x + p2[1]*uc.y + p3[0]*uc.z + p3[1]*uc.w;
            }
            union { unsigned int u4[4]; bf16x8 v8; } av;
            av.u4[0] = __builtin_amdgcn_perm(__float_as_uint(p0[1]), __float_as_uint(p0[0]), 0x07060302);
            av.u4[1] = __builtin_amdgcn_perm(__float_as_uint(p1[1]), __float_as_uint(p1[0]), 0x07060302);
            av.u4[2] = __builtin_amdgcn_perm(__float_as_uint(p2[1]), __float_as_uint(p2[0]), 0x07060302);
            av.u4[3] = __builtin_amdgcn_perm(__float_as_uint(p3[1]), __float_as_uint(p3[0]), 0x07060302);
            const unsigned char* yb = YsB + (wc * 32 + l31) * YP
                                    + (kk * 16 + lh * 8) * 2;
            union { uint2 u2[2]; bf16x8 v8; } bv;
            bv.u2[0] = *(const uint2*)(yb);
            bv.u2[1] = *(const uint2*)(yb + 8);
            acc = __builtin_amdgcn_mfma_f32_32x32x16_bf16(av.v8, bv.v8, acc, 0, 0, 0);
        }
    }
    ds += __shfl_down(ds, 32);
    if (wc == 0 && lh == 0)
        dpart[((size_t)nc * BB + b) * NN + mt * 64 + wr * 32 + l31] = ds;
    float* pb = pbuf + (((size_t)nc * BB + b) * NN + mt * 64 + wr * 32) * DD
              + wc * 32 + l31;
    #pragma unroll
    for (int r = 0; r < 16; ++r) {
        const int row = (r & 3) + 8 * (r >> 2) + 4 * lh;
        pb[(size_t)row * DD] = acc[r];
    }
}

// ---------------------------------------------------------------- out_reduce
__global__ __launch_bounds__(256) void out_reduce(const float* __restrict__ pbuf,
                                                  const float* __restrict__ dpart,
                                                  const float* __restrict__ u,
                                                  const float* __restrict__ X,
                                                  float* __restrict__ outP) {
    const int idx = blockIdx.x * 256 + threadIdx.x;   // per float4
    const int d4 = idx & (DD / 4 - 1);
    const int bm = idx >> 4;                           // b*NN + m
    float4 s = make_float4(0.f, 0.f, 0.f, 0.f);
    float denom = 0.f;
    #pragma unroll
    for (int nc = 0; nc < NC; ++nc) {
        float4 p = *(const float4*)(pbuf + (size_t)nc * BB * NN * DD
                                    + (size_t)bm * DD + d4 * 4);
        s.x += p.x; s.y += p.y; s.z += p.z; s.w += p.w;
        denom += dpart[(size_t)nc * BB * NN + bm];
    }
    const float um = KSCALE * u[bm];
    denom += um;
    float4 xx = *(const float4*)(X + (size_t)bm * DD + d4 * 4);
    s.x += um * xx.x; s.y += um * xx.y; s.z += um * xx.z; s.w += um * xx.w;
    const float inv = 1.0f / denom;
    *(float4*)(outP + (size_t)bm * DD + d4 * 4) =
        make_float4(inv * s.x, inv * s.y, inv * s.z, inv * s.w);
}

// ---------------------------------------------------------------- launch
extern "C" void kernel_launch(void* const* d_in, const int* in_sizes, int n_in,
                              void* d_out, int out_size, void* d_ws, size_t ws_size,
                              hipStream_t stream) {
    const float* X = (const float*)d_in[0];   // particles [B,N,D]
    const float* W = (const float*)d_in[1];   // weights   [B,N]
    float* outP = (float*)d_out;                       // [B,N,D]
    float* outW = outP + (size_t)BB * NN * DD;         // [B,N]

    float* ws = (float*)d_ws;
    const size_t nfloats = (size_t)BB * NN          // sq
                         + 16                       // scale
                         + 2 * (size_t)BB * NN      // u, v
                         + (size_t)BB * 32 * 64 + BB * 32   // pcol, ptot
                         + (size_t)NC * BB * NN * DD        // pbuf
                         + (size_t)NC * BB * NN             // dpart
                         + 256;                             // ctr (ints)
    const size_t need = nfloats * 4
                      + (size_t)BB * NN * DD * 2    // Xbf
                      + (size_t)BB * DD * NN * 2    // Yt
                      + (size_t)BB * NN * NN;       // K fp8
    if (ws_size < need) return;

    float* sq    = ws;
    float* scale = sq + (size_t)BB * NN;
    float* u     = scale + 16;
    float* v     = u + (size_t)BB * NN;
    float* pcol  = v + (size_t)BB * NN;
    float* ptot  = pcol + (size_t)BB * 32 * 64;
    float* pbuf  = ptot + BB * 32;
    float* dpart = pbuf + (size_t)NC * BB * NN * DD;
    int*   ctr   = (int*)(dpart + (size_t)NC * BB * NN);
    unsigned short* Xbf = (unsigned short*)(ctr + 256);
    unsigned short* Yt  = Xbf + (size_t)BB * NN * DD;
    unsigned char*  K   = (unsigned char*)(Yt + (size_t)BB * DD * NN);

    stats1<<<dim3(BB * 32), 256, 0, stream>>>(X, Xbf, sq, pcol, ptot, outW);
    stats2<<<dim3(BB), 64, 0, stream>>>(pcol, ptot, scale);
    build_K<<<dim3(528 * BB), 256, 0, stream>>>(Xbf, sq, scale, K);
    zero_ctr<<<dim3(1), 256, 0, stream>>>(ctr);
    {
        const unsigned char* Kc = K;
        void* args[] = {(void*)&Kc, (void*)&W, (void*)&u, (void*)&v, (void*)&ctr};
        hipError_t ce = hipLaunchCooperativeKernel((const void*)sink_all,
                                                   dim3(BB * CPB), dim3(256),
                                                   args, 0, stream);
        if (ce != hipSuccess) {
            // Fallback: classic 19-launch chain (same math, same quantized K).
            sink_pass<2><<<dim3(BB * NN / 8), 256, 0, stream>>>(K, u, W, u);  // u1
            for (int i = 0; i < 9; ++i) {
                sink_pass<1><<<dim3(BB * NN / 8), 256, 0, stream>>>(K, u, W, v);
                sink_pass<0><<<dim3(BB * NN / 8), 256, 0, stream>>>(K, v, W, u);
            }
        }
    }
    yprep<<<dim3(BB * NN / 64), 256, 0, stream>>>(X, u, Yt);
    out_gemm<<<dim3((NN / 64) * NC * BB), 256, 0, stream>>>(K, Yt, u, pbuf, dpart);
    out_reduce<<<dim3(BB * NN * DD / 4 / 256), 256, 0, stream>>>(pbuf, dpart, u, X, outP);
}

// Round 13
// 165.170 us; speedup vs baseline: 13.2030x; 13.2030x over previous
//
#include <hip/hip_runtime.h>

#define BB 8
#define NN 2048
#define DD 64
#define NC 4            // split-K chunks for out_gemm
constexpr float EPS = 0.1f;
constexpr float KSCALE = 4096.0f;   // off-diag fp8 scale; diag handled analytically

typedef short bf16x8 __attribute__((ext_vector_type(8)));
typedef float f32x16 __attribute__((ext_vector_type(16)));
typedef float f32x2  __attribute__((ext_vector_type(2)));

// ---------------------------------------------------------------- fp8 helpers
__device__ inline float e4m3_to_f32_manual(unsigned int b) {
    unsigned int e = (b >> 3) & 15u, m = b & 7u;
    float v;
    if (e == 0) v = (float)m * 0.001953125f;              // m * 2^-9
    else        v = __uint_as_float(((e + 120u) << 23) | (m << 20));
    return (b & 0x80u) ? -v : v;
}

template <bool HI>
__device__ inline f32x2 cvt2_fp8(unsigned int w) {
#if __has_builtin(__builtin_amdgcn_cvt_pk_f32_fp8)
    return __builtin_amdgcn_cvt_pk_f32_fp8(w, HI);
#else
    f32x2 r; unsigned int s = HI ? (w >> 16) : w;
    r[0] = e4m3_to_f32_manual(s & 255u);
    r[1] = e4m3_to_f32_manual((s >> 8) & 255u);
    return r;
#endif
}

__device__ inline unsigned char f32_to_e4m3(float f) {   // f in [0, 448]
#if __has_builtin(__builtin_amdgcn_cvt_pk_fp8_f32)
    return (unsigned char)(__builtin_amdgcn_cvt_pk_fp8_f32(f, f, 0, false) & 0xFF);
#else
    if (!(f > 0.f)) return 0;
    if (f >= 448.f) return 0x7E;
    int e; float m = frexpf(f, &e);            // f = m*2^e, m in [0.5,1)
    if (e >= -5) {                              // normal: f >= 2^-6
        int mant = (int)roundf(m * 16.f) - 8;   // 0..8
        int ef = e + 6;
        if (mant == 8) { mant = 0; ef += 1; }
        if (ef >= 16) return 0x7E;
        return (unsigned char)((ef << 3) | mant);
    }
    int mant = (int)roundf(f * 512.f);          // subnormal
    if (mant >= 8) return 0x08;
    return (unsigned char)mant;
#endif
}

__device__ inline unsigned int pack4_e4m3(float a, float b, float c, float d) {
#if __has_builtin(__builtin_amdgcn_cvt_pk_fp8_f32)
    unsigned int w = 0;
    w = (unsigned int)__builtin_amdgcn_cvt_pk_fp8_f32(a, b, (int)w, false);
    w = (unsigned int)__builtin_amdgcn_cvt_pk_fp8_f32(c, d, (int)w, true);
    return w;
#else
    return (unsigned int)f32_to_e4m3(a) | ((unsigned int)f32_to_e4m3(b) << 8)
         | ((unsigned int)f32_to_e4m3(c) << 16) | ((unsigned int)f32_to_e4m3(d) << 24);
#endif
}

__device__ inline unsigned short f2bf_rne(float f) {
    unsigned int u = __float_as_uint(f);
    u += 0x7FFFu + ((u >> 16) & 1u);
    return (unsigned short)(u >> 16);
}

// ---------------------------------------------------------------- stats1
// Also initializes outW (folded former init_w launch).
__global__ __launch_bounds__(256) void stats1(const float* __restrict__ X,
                                              unsigned short* __restrict__ Xbf,
                                              float* __restrict__ sq,
                                              float* __restrict__ pcol,
                                              float* __restrict__ ptot,
                                              float* __restrict__ outW) {
    const int blk = blockIdx.x;          // 0 .. BB*32-1
    const int b   = blk & 7;
    const int ch  = blk >> 3;            // 0..31
    const int r0  = ch * 64;
    const int t = threadIdx.x, w = t >> 6, lane = t & 63;
    const int gidx = blk * 256 + t;
    if (gidx < BB * NN) outW[gidx] = 1.0f / (float)NN;
    const float* Xb = X + (size_t)b * NN * DD;
    unsigned short* Xbfb = Xbf + (size_t)b * NN * DD;
    float cs = 0.f, sqtot = 0.f;
    #pragma unroll
    for (int i = w; i < 64; i += 4) {
        const int row = r0 + i;
        float x = Xb[(size_t)row * DD + lane];
        unsigned short hb = f2bf_rne(x);
        Xbfb[(size_t)row * DD + lane] = hb;
        float xr = __uint_as_float((unsigned int)hb << 16);
        cs += xr;
        float s = xr * xr;
        #pragma unroll
        for (int off = 32; off > 0; off >>= 1) s += __shfl_down(s, off);
        if (lane == 0) { sq[b * NN + row] = s; sqtot += s; }
    }
    __shared__ float colS[4][64];
    __shared__ float totS[4];
    colS[w][lane] = cs;
    if (lane == 0) totS[w] = sqtot;
    __syncthreads();
    if (t < 64)
        pcol[(b * 32 + ch) * 64 + t] = colS[0][t] + colS[1][t] + colS[2][t] + colS[3][t];
    if (t == 0)
        ptot[b * 32 + ch] = totS[0] + totS[1] + totS[2] + totS[3];
}

// ---------------------------------------------------------------- stats2
__global__ void stats2(const float* __restrict__ pcol,
                       const float* __restrict__ ptot,
                       float* __restrict__ scale) {
    const int b = blockIdx.x, t = threadIdx.x;   // 64 threads
    float c = 0.f;
    #pragma unroll
    for (int p = 0; p < 32; ++p) c += pcol[(b * 32 + p) * 64 + t];
    float s2 = c * c;
    #pragma unroll
    for (int off = 32; off > 0; off >>= 1) s2 += __shfl_down(s2, off);
    if (t == 0) {
        float T = 0.f;
        #pragma unroll
        for (int p = 0; p < 32; ++p) T += ptot[b * 32 + p];
        float cmean = 2.0f * T / (float)NN
                    - 2.0f * s2 / ((float)NN * (float)NN) + 1e-8f;
        scale[b] = -1.0f / (cmean * EPS);
    }
}

// ---------------------------------------------------------------- build_K
// SYMMETRIC: one block per unordered tile pair (I<=J) per batch (528*8 blocks).
// Computes the 64x64 gram once, writes K[I,J] AND transpose K[J,I] from LDS.
// Emits rsum row-sums + col-sums for the free u1 (v=1) pass.
__global__ __launch_bounds__(256) void build_K(const unsigned short* __restrict__ Xbf,
                                               const float* __restrict__ sq,
                                               const float* __restrict__ scale,
                                               unsigned char* __restrict__ K,
                                               float* __restrict__ rsum) {
    __shared__ float T[64][68];
    const int bid = blockIdx.x;                   // 0..4223
    const int b = bid & 7;
    int q = bid >> 3, I = 0;                      // triangular decode (uniform)
    while (q >= 32 - I) { q -= 32 - I; ++I; }
    const int J = I + q;                          // I <= J
    const int t = threadIdx.x, w = t >> 6;
    const int lane = t & 63, l31 = lane & 31, lh = lane >> 5;
    const int wr = w >> 1, wc = w & 1;            // 32x32 quadrant of 64x64 tile
    const unsigned short* Xb = Xbf + (size_t)b * NN * DD;
    const int n_row = I * 64 + wr * 32 + l31;     // A: lane holds row l31 (I side)
    const int m_row = J * 64 + wc * 32 + l31;     // B: lane holds col l31 (J side)
    bf16x8 af[4], bf[4];
    #pragma unroll
    for (int s = 0; s < 4; ++s) {                 // k = s*16 + lh*8 + (0..7)
        af[s] = *(const bf16x8*)(Xb + (size_t)n_row * DD + s * 16 + lh * 8);
        bf[s] = *(const bf16x8*)(Xb + (size_t)m_row * DD + s * 16 + lh * 8);
    }
    f32x16 acc = {};
    #pragma unroll
    for (int s = 0; s < 4; ++s)
        acc = __builtin_amdgcn_mfma_f32_32x32x16_bf16(af[s], bf[s], acc, 0, 0, 0);
    // C/D: col = l31, row = (r&3) + 8*(r>>2) + 4*lh   [m74/m101 verified]
    const float sc = scale[b];
    const float* sqb = sq + b * NN;
    const int gm = J * 64 + wc * 32 + l31;
    const float sqm = sqb[gm];
    #pragma unroll
    for (int r = 0; r < 16; ++r) {
        const int row = (r & 3) + 8 * (r >> 2) + 4 * lh;
        const int gn = I * 64 + wr * 32 + row;
        float val = KSCALE * __expf(sc * (sqb[gn] + sqm - 2.0f * acc[r]));
        T[wr * 32 + row][wc * 32 + l31] = (gn == gm) ? 0.0f : val;
    }
    __syncthreads();
    unsigned char* Kb = K + (size_t)b * NN * NN;
    // ---- store 1: K[I-rows][J-cols], row-major from LDS, + row-sums
    {
        const int orow = t >> 2, oseg = t & 3;    // 64 rows x 4 segs of 16
        float vv[16];
        #pragma unroll
        for (int j = 0; j < 4; ++j)
            *(float4*)&vv[j * 4] = *(const float4*)&T[orow][oseg * 16 + j * 4];
        float rs = 0.f;
        #pragma unroll
        for (int j = 0; j < 16; ++j) rs += vv[j];
        rs += __shfl_down(rs, 2);
        rs += __shfl_down(rs, 1);
        if (oseg == 0)
            rsum[((size_t)b * 32 + J) * NN + I * 64 + orow] = rs;
        uint4 o;
        o.x = pack4_e4m3(vv[0],  vv[1],  vv[2],  vv[3]);
        o.y = pack4_e4m3(vv[4],  vv[5],  vv[6],  vv[7]);
        o.z = pack4_e4m3(vv[8],  vv[9],  vv[10], vv[11]);
        o.w = pack4_e4m3(vv[12], vv[13], vv[14], vv[15]);
        *(uint4*)(Kb + (size_t)(I * 64 + orow) * NN + J * 64 + oseg * 16) = o;
    }
    // ---- store 2 (I<J only): transpose tile -> K[J-rows][I-cols], + col-sums
    if (I != J) {
        const int c = t >> 2, rseg = t & 3;       // 64 cols x 4 segs of 16 rows
        float vv[16];
        #pragma unroll
        for (int j = 0; j < 16; ++j) vv[j] = T[rseg * 16 + j][c];
        float csum = 0.f;
        #pragma unroll
        for (int j = 0; j < 16; ++j) csum += vv[j];
        csum += __shfl_down(csum, 2);
        csum += __shfl_down(csum, 1);
        if (rseg == 0)
            rsum[((size_t)b * 32 + I) * NN + J * 64 + c] = csum;
        uint4 o;
        o.x = pack4_e4m3(vv[0],  vv[1],  vv[2],  vv[3]);
        o.y = pack4_e4m3(vv[4],  vv[5],  vv[6],  vv[7]);
        o.z = pack4_e4m3(vv[8],  vv[9],  vv[10], vv[11]);
        o.w = pack4_e4m3(vv[12], vv[13], vv[14], vv[15]);
        *(uint4*)(Kb + (size_t)(J * 64 + c) * NN + I * 64 + rseg * 16) = o;
    }
}

// ---------------------------------------------------------------- ucombine
// u1[b,n] = (w+1e-16) / ( sum_g rsum[b][g][n] + KSCALE )   (v=1 pass, free)
__global__ __launch_bounds__(256) void ucombine(const float* __restrict__ rsum,
                                                const float* __restrict__ W,
                                                float* __restrict__ u) {
    const int idx = blockIdx.x * 256 + threadIdx.x;   // 0..16383
    const int b = idx >> 11, n = idx & (NN - 1);
    float s = 0.f;
    #pragma unroll
    for (int g = 0; g < 32; ++g)
        s += rsum[((size_t)b * 32 + g) * NN + n];
    u[idx] = (W[idx] + 1e-16f) / (s + KSCALE);
}

// ---------------------------------------------------------------- sink_pass
// MODE 0: u[n] = (w[n]+1e-16) / ( sum_m K8[n,m]*v[m] + KSCALE*v[n] )
// MODE 1: v[m] = (1/N)        / ( sum_n K8[m,n]*u[n] + KSCALE*u[m] )
template <int MODE>
__global__ __launch_bounds__(256) void sink_pass(const unsigned char* __restrict__ K,
                                                 const float* __restrict__ vin,
                                                 const float* __restrict__ wts,
                                                 float* __restrict__ out) {
    __shared__ float vs[NN];
    const int bid = blockIdx.x;                   // 0..2047
    const int b = bid & 7, j = bid >> 3;          // j 0..255
    const int t = threadIdx.x, w = t >> 6, lane = t & 63;
    const float* vb = vin + (size_t)b * NN;
    #pragma unroll
    for (int s = 0; s < 2; ++s)
        *(float4*)&vs[(t + s * 256) * 4] = *(const float4*)&vb[(t + s * 256) * 4];
    __syncthreads();
    const int r0 = j * 8 + w * 2;                 // 2 rows per wave
    const unsigned char* Kr0 = K + ((size_t)b * NN + r0) * NN;
    const unsigned char* Kr1 = Kr0 + NN;
    float a0 = 0.f, a1 = 0.f;
    #pragma unroll
    for (int it = 0; it < 2; ++it) {
        const int m0 = it * 1024 + lane * 16;
        const uint4 ka = *(const uint4*)(Kr0 + m0);
        const uint4 kb = *(const uint4*)(Kr1 + m0);
        const float4 v0 = *(const float4*)&vs[m0];
        const float4 v1 = *(const float4*)&vs[m0 + 4];
        const float4 v2 = *(const float4*)&vs[m0 + 8];
        const float4 v3 = *(const float4*)&vs[m0 + 12];
        {
            f32x2 q0 = cvt2_fp8<false>(ka.x), q1 = cvt2_fp8<true>(ka.x);
            f32x2 q2 = cvt2_fp8<false>(ka.y), q3 = cvt2_fp8<true>(ka.y);
            f32x2 q4 = cvt2_fp8<false>(ka.z), q5 = cvt2_fp8<true>(ka.z);
            f32x2 q6 = cvt2_fp8<false>(ka.w), q7 = cvt2_fp8<true>(ka.w);
            a0 += q0[0]*v0.x + q0[1]*v0.y + q1[0]*v0.z + q1[1]*v0.w
                + q2[0]*v1.x + q2[1]*v1.y + q3[0]*v1.z + q3[1]*v1.w
                + q4[0]*v2.x + q4[1]*v2.y + q5[0]*v2.z + q5[1]*v2.w
                + q6[0]*v3.x + q6[1]*v3.y + q7[0]*v3.z + q7[1]*v3.w;
        }
        {
            f32x2 q0 = cvt2_fp8<false>(kb.x), q1 = cvt2_fp8<true>(kb.x);
            f32x2 q2 = cvt2_fp8<false>(kb.y), q3 = cvt2_fp8<true>(kb.y);
            f32x2 q4 = cvt2_fp8<false>(kb.z), q5 = cvt2_fp8<true>(kb.z);
            f32x2 q6 = cvt2_fp8<false>(kb.w), q7 = cvt2_fp8<true>(kb.w);
            a1 += q0[0]*v0.x + q0[1]*v0.y + q1[0]*v0.z + q1[1]*v0.w
                + q2[0]*v1.x + q2[1]*v1.y + q3[0]*v1.z + q3[1]*v1.w
                + q4[0]*v2.x + q4[1]*v2.y + q5[0]*v2.z + q5[1]*v2.w
                + q6[0]*v3.x + q6[1]*v3.y + q7[0]*v3.z + q7[1]*v3.w;
        }
    }
    #pragma unroll
    for (int off = 32; off > 0; off >>= 1) {
        a0 += __shfl_down(a0, off);
        a1 += __shfl_down(a1, off);
    }
    if (lane == 0) {
        const float n0 = (MODE == 0) ? (wts[(size_t)b*NN + r0] + 1e-16f) : (1.0f/(float)NN);
        const float n1 = (MODE == 0) ? (wts[(size_t)b*NN + r0 + 1] + 1e-16f) : (1.0f/(float)NN);
        out[(size_t)b * NN + r0]     = n0 / (a0 + KSCALE * vs[r0]);
        out[(size_t)b * NN + r0 + 1] = n1 / (a1 + KSCALE * vs[r0 + 1]);
    }
}

// ---------------------------------------------------------------- yprep
// Yt[b][d][n] = bf16( u[b][n] * X[b][n][d] )   (transposed for MFMA B-frags)
__global__ __launch_bounds__(256) void yprep(const float* __restrict__ X,
                                             const float* __restrict__ u,
                                             unsigned short* __restrict__ Yt) {
    __shared__ float T[64][65];
    const int bid = blockIdx.x;                   // 0..255
    const int b = bid & 7, nt = bid >> 3;
    const int t = threadIdx.x;
    const int nl = t >> 2, c0 = (t & 3) << 4;
    const float* Xb = X + ((size_t)b * NN + nt * 64) * DD;
    const float uu = u[(size_t)b * NN + nt * 64 + nl];
    #pragma unroll
    for (int j = 0; j < 4; ++j) {
        float4 x = *(const float4*)(Xb + (size_t)nl * DD + c0 + j * 4);
        T[c0 + j * 4 + 0][nl] = uu * x.x;
        T[c0 + j * 4 + 1][nl] = uu * x.y;
        T[c0 + j * 4 + 2][nl] = uu * x.z;
        T[c0 + j * 4 + 3][nl] = uu * x.w;
    }
    __syncthreads();
    const int d = t >> 2, n0 = (t & 3) << 4;
    unsigned short* Yr = Yt + ((size_t)b * DD + d) * NN + nt * 64 + n0;
    unsigned int ow[8];
    #pragma unroll
    for (int j = 0; j < 8; ++j) {
        unsigned int lo = f2bf_rne(T[d][n0 + 2 * j]);
        unsigned int hi = f2bf_rne(T[d][n0 + 2 * j + 1]);
        ow[j] = lo | (hi << 16);
    }
    *(uint4*)(Yr)     = make_uint4(ow[0], ow[1], ow[2], ow[3]);
    *(uint4*)(Yr + 8) = make_uint4(ow[4], ow[5], ow[6], ow[7]);
}

// ---------------------------------------------------------------- out_gemm
// pbuf[nc,b,m,d] = sum_{n in chunk} K8[m,n]*u[n]*x[n,d]  via bf16 MFMA.
// LDS-staged K and Y tiles; dpart side-channel fuses the final v-update.
#define KP 136
#define YP 264
__global__ __launch_bounds__(256) void out_gemm(const unsigned char* __restrict__ K,
                                                const unsigned short* __restrict__ Yt,
                                                const float* __restrict__ u,
                                                float* __restrict__ pbuf,
                                                float* __restrict__ dpart) {
    __shared__ __align__(16) unsigned char KsB[64 * KP];
    __shared__ __align__(16) unsigned char YsB[64 * YP];
    const int bid = blockIdx.x;                   // 0..1023
    const int b = bid & 7, tix = bid >> 3;        // tix 0..127
    const int nc = tix & (NC - 1), mt = tix >> 2; // mt 0..31
    const int t = threadIdx.x, w = t >> 6, lane = t & 63;
    const int l31 = lane & 31, lh = lane >> 5;
    const int wr = w >> 1, wc = w & 1;
    const unsigned char*  Kb = K + (size_t)b * NN * NN + (size_t)(mt * 64) * NN;
    const unsigned short* Yb = Yt + (size_t)b * DD * NN;
    const float* ub = u + (size_t)b * NN;
    f32x16 acc = {};
    float ds = 0.f;
    for (int st = 0; st < (NN / NC) / 128; ++st) {
        const int n0 = nc * (NN / NC) + st * 128;
        __syncthreads();
        #pragma unroll
        for (int i = 0; i < 2; ++i) {             // K tile: 64 rows x 128 B
            const int f = t + i * 256;            // 0..511
            const int row = f >> 3, seg = (f & 7) * 16;
            *(uint4*)(KsB + row * KP + seg) =
                *(const uint4*)(Kb + (size_t)row * NN + n0 + seg);
        }
        #pragma unroll
        for (int i = 0; i < 4; ++i) {             // Y tile: 64 rows x 128 bf16
            const int f = t + i * 256;            // 0..1023
            const int row = f >> 4, sege = (f & 15) * 8;
            *(uint4*)(YsB + row * YP + sege * 2) =
                *(const uint4*)(Yb + (size_t)row * NN + n0 + sege);
        }
        __syncthreads();
        #pragma unroll
        for (int kk = 0; kk < 8; ++kk) {
            const uint2 k8 = *(const uint2*)(KsB + (wr * 32 + l31) * KP
                                             + kk * 16 + lh * 8);
            f32x2 p0 = cvt2_fp8<false>(k8.x);
            f32x2 p1 = cvt2_fp8<true>(k8.x);
            f32x2 p2 = cvt2_fp8<false>(k8.y);
            f32x2 p3 = cvt2_fp8<true>(k8.y);
            if (wc == 0) {
                const int nu = n0 + kk * 16 + lh * 8;
                const float4 ua = *(const float4*)(ub + nu);
                const float4 uc = *(const float4*)(ub + nu + 4);
                ds += p0[0]*ua.x + p0[1]*ua.y + p1[0]*ua.z + p1[1]*ua.w
                    + p2[0]*uc.x + p2[1]*uc.y + p3[0]*uc.z + p3[1]*uc.w;
            }
            union { unsigned int u4[4]; bf16x8 v8; } av;
            av.u4[0] = __builtin_amdgcn_perm(__float_as_uint(p0[1]), __float_as_uint(p0[0]), 0x07060302);
            av.u4[1] = __builtin_amdgcn_perm(__float_as_uint(p1[1]), __float_as_uint(p1[0]), 0x07060302);
            av.u4[2] = __builtin_amdgcn_perm(__float_as_uint(p2[1]), __float_as_uint(p2[0]), 0x07060302);
            av.u4[3] = __builtin_amdgcn_perm(__float_as_uint(p3[1]), __float_as_uint(p3[0]), 0x07060302);
            const unsigned char* yb = YsB + (wc * 32 + l31) * YP
                                    + (kk * 16 + lh * 8) * 2;
            union { uint2 u2[2]; bf16x8 v8; } bv;
            bv.u2[0] = *(const uint2*)(yb);
            bv.u2[1] = *(const uint2*)(yb + 8);
            acc = __builtin_amdgcn_mfma_f32_32x32x16_bf16(av.v8, bv.v8, acc, 0, 0, 0);
        }
    }
    ds += __shfl_down(ds, 32);
    if (wc == 0 && lh == 0)
        dpart[((size_t)nc * BB + b) * NN + mt * 64 + wr * 32 + l31] = ds;
    float* pb = pbuf + (((size_t)nc * BB + b) * NN + mt * 64 + wr * 32) * DD
              + wc * 32 + l31;
    #pragma unroll
    for (int r = 0; r < 16; ++r) {
        const int row = (r & 3) + 8 * (r >> 2) + 4 * lh;
        pb[(size_t)row * DD] = acc[r];
    }
}

// ---------------------------------------------------------------- out_reduce
__global__ __launch_bounds__(256) void out_reduce(const float* __restrict__ pbuf,
                                                  const float* __restrict__ dpart,
                                                  const float* __restrict__ u,
                                                  const float* __restrict__ X,
                                                  float* __restrict__ outP) {
    const int idx = blockIdx.x * 256 + threadIdx.x;   // per float4
    const int d4 = idx & (DD / 4 - 1);
    const int bm = idx >> 4;                           // b*NN + m
    float4 s = make_float4(0.f, 0.f, 0.f, 0.f);
    float denom = 0.f;
    #pragma unroll
    for (int nc = 0; nc < NC; ++nc) {
        float4 p = *(const float4*)(pbuf + (size_t)nc * BB * NN * DD
                                    + (size_t)bm * DD + d4 * 4);
        s.x += p.x; s.y += p.y; s.z += p.z; s.w += p.w;
        denom += dpart[(size_t)nc * BB * NN + bm];
    }
    const float um = KSCALE * u[bm];
    denom += um;
    float4 xx = *(const float4*)(X + (size_t)bm * DD + d4 * 4);
    s.x += um * xx.x; s.y += um * xx.y; s.z += um * xx.z; s.w += um * xx.w;
    const float inv = 1.0f / denom;
    *(float4*)(outP + (size_t)bm * DD + d4 * 4) =
        make_float4(inv * s.x, inv * s.y, inv * s.z, inv * s.w);
}

// ---------------------------------------------------------------- launch
extern "C" void kernel_launch(void* const* d_in, const int* in_sizes, int n_in,
                              void* d_out, int out_size, void* d_ws, size_t ws_size,
                              hipStream_t stream) {
    const float* X = (const float*)d_in[0];   // particles [B,N,D]
    const float* W = (const float*)d_in[1];   // weights   [B,N]
    float* outP = (float*)d_out;                       // [B,N,D]
    float* outW = outP + (size_t)BB * NN * DD;         // [B,N]

    float* ws = (float*)d_ws;
    const size_t nfloats = (size_t)BB * NN          // sq
                         + 16                       // scale
                         + 2 * (size_t)BB * NN      // u, v
                         + (size_t)BB * 32 * 64 + BB * 32   // pcol, ptot
                         + (size_t)NC * BB * NN * DD        // pbuf
                         + (size_t)BB * 32 * NN             // rsum
                         + (size_t)NC * BB * NN;            // dpart
    const size_t need = nfloats * 4
                      + (size_t)BB * NN * DD * 2    // Xbf
                      + (size_t)BB * DD * NN * 2    // Yt
                      + (size_t)BB * NN * NN;       // K fp8
    if (ws_size < need) return;

    float* sq    = ws;
    float* scale = sq + (size_t)BB * NN;
    float* u     = scale + 16;
    float* v     = u + (size_t)BB * NN;
    float* pcol  = v + (size_t)BB * NN;
    float* ptot  = pcol + (size_t)BB * 32 * 64;
    float* pbuf  = ptot + BB * 32;
    float* rsum  = pbuf + (size_t)NC * BB * NN * DD;
    float* dpart = rsum + (size_t)BB * 32 * NN;
    unsigned short* Xbf = (unsigned short*)(dpart + (size_t)NC * BB * NN);
    unsigned short* Yt  = Xbf + (size_t)BB * NN * DD;
    unsigned char*  K   = (unsigned char*)(Yt + (size_t)BB * DD * NN);

    stats1<<<dim3(BB * 32), 256, 0, stream>>>(X, Xbf, sq, pcol, ptot, outW);
    stats2<<<dim3(BB), 64, 0, stream>>>(pcol, ptot, scale);
    build_K<<<dim3(528 * BB), 256, 0, stream>>>(Xbf, sq, scale, K, rsum);
    ucombine<<<dim3(BB * NN / 256), 256, 0, stream>>>(rsum, W, u);   // u1 (v=1)
    for (int i = 0; i < 9; ++i) {
        sink_pass<1><<<dim3(BB * NN / 8), 256, 0, stream>>>(K, u, W, v);  // v_i
        sink_pass<0><<<dim3(BB * NN / 8), 256, 0, stream>>>(K, v, W, u);  // u_{i+1}
    }
    yprep<<<dim3(BB * NN / 64), 256, 0, stream>>>(X, u, Yt);
    out_gemm<<<dim3((NN / 64) * NC * BB), 256, 0, stream>>>(K, Yt, u, pbuf, dpart);
    out_reduce<<<dim3(BB * NN * DD / 4 / 256), 256, 0, stream>>>(pbuf, dpart, u, X, outP);
}

// Round 14
// 156.516 us; speedup vs baseline: 13.9330x; 1.0553x over previous
//
#include <hip/hip_runtime.h>

#define BB 8
#define NN 2048
#define DD 64
#define NC 4            // split-K chunks for out_gemm
constexpr float EPS = 0.1f;
constexpr float KSCALE = 4096.0f;   // off-diag fp8 scale; diag handled analytically

typedef short bf16x8 __attribute__((ext_vector_type(8)));
typedef float f32x16 __attribute__((ext_vector_type(16)));
typedef float f32x2  __attribute__((ext_vector_type(2)));

// ---------------------------------------------------------------- fp8 helpers
__device__ inline float e4m3_to_f32_manual(unsigned int b) {
    unsigned int e = (b >> 3) & 15u, m = b & 7u;
    float v;
    if (e == 0) v = (float)m * 0.001953125f;              // m * 2^-9
    else        v = __uint_as_float(((e + 120u) << 23) | (m << 20));
    return (b & 0x80u) ? -v : v;
}

template <bool HI>
__device__ inline f32x2 cvt2_fp8(unsigned int w) {
#if __has_builtin(__builtin_amdgcn_cvt_pk_f32_fp8)
    return __builtin_amdgcn_cvt_pk_f32_fp8(w, HI);
#else
    f32x2 r; unsigned int s = HI ? (w >> 16) : w;
    r[0] = e4m3_to_f32_manual(s & 255u);
    r[1] = e4m3_to_f32_manual((s >> 8) & 255u);
    return r;
#endif
}

__device__ inline unsigned char f32_to_e4m3(float f) {   // f in [0, 448]
#if __has_builtin(__builtin_amdgcn_cvt_pk_fp8_f32)
    return (unsigned char)(__builtin_amdgcn_cvt_pk_fp8_f32(f, f, 0, false) & 0xFF);
#else
    if (!(f > 0.f)) return 0;
    if (f >= 448.f) return 0x7E;
    int e; float m = frexpf(f, &e);            // f = m*2^e, m in [0.5,1)
    if (e >= -5) {                              // normal: f >= 2^-6
        int mant = (int)roundf(m * 16.f) - 8;   // 0..8
        int ef = e + 6;
        if (mant == 8) { mant = 0; ef += 1; }
        if (ef >= 16) return 0x7E;
        return (unsigned char)((ef << 3) | mant);
    }
    int mant = (int)roundf(f * 512.f);          // subnormal
    if (mant >= 8) return 0x08;
    return (unsigned char)mant;
#endif
}

__device__ inline unsigned int pack4_e4m3(float a, float b, float c, float d) {
#if __has_builtin(__builtin_amdgcn_cvt_pk_fp8_f32)
    unsigned int w = 0;
    w = (unsigned int)__builtin_amdgcn_cvt_pk_fp8_f32(a, b, (int)w, false);
    w = (unsigned int)__builtin_amdgcn_cvt_pk_fp8_f32(c, d, (int)w, true);
    return w;
#else
    return (unsigned int)f32_to_e4m3(a) | ((unsigned int)f32_to_e4m3(b) << 8)
         | ((unsigned int)f32_to_e4m3(c) << 16) | ((unsigned int)f32_to_e4m3(d) << 24);
#endif
}

__device__ inline unsigned short f2bf_rne(float f) {
    unsigned int u = __float_as_uint(f);
    u += 0x7FFFu + ((u >> 16) & 1u);
    return (unsigned short)(u >> 16);
}

// ---------------------------------------------------------------- stats1
// Also initializes outW (folded former init_w launch).
__global__ __launch_bounds__(256) void stats1(const float* __restrict__ X,
                                              unsigned short* __restrict__ Xbf,
                                              float* __restrict__ sq,
                                              float* __restrict__ pcol,
                                              float* __restrict__ ptot,
                                              float* __restrict__ outW) {
    const int blk = blockIdx.x;          // 0 .. BB*32-1
    const int b   = blk & 7;
    const int ch  = blk >> 3;            // 0..31
    const int r0  = ch * 64;
    const int t = threadIdx.x, w = t >> 6, lane = t & 63;
    const int gidx = blk * 256 + t;
    if (gidx < BB * NN) outW[gidx] = 1.0f / (float)NN;
    const float* Xb = X + (size_t)b * NN * DD;
    unsigned short* Xbfb = Xbf + (size_t)b * NN * DD;
    float cs = 0.f, sqtot = 0.f;
    #pragma unroll
    for (int i = w; i < 64; i += 4) {
        const int row = r0 + i;
        float x = Xb[(size_t)row * DD + lane];
        unsigned short hb = f2bf_rne(x);
        Xbfb[(size_t)row * DD + lane] = hb;
        float xr = __uint_as_float((unsigned int)hb << 16);
        cs += xr;
        float s = xr * xr;
        #pragma unroll
        for (int off = 32; off > 0; off >>= 1) s += __shfl_down(s, off);
        if (lane == 0) { sq[b * NN + row] = s; sqtot += s; }
    }
    __shared__ float colS[4][64];
    __shared__ float totS[4];
    colS[w][lane] = cs;
    if (lane == 0) totS[w] = sqtot;
    __syncthreads();
    if (t < 64)
        pcol[(b * 32 + ch) * 64 + t] = colS[0][t] + colS[1][t] + colS[2][t] + colS[3][t];
    if (t == 0)
        ptot[b * 32 + ch] = totS[0] + totS[1] + totS[2] + totS[3];
}

// ---------------------------------------------------------------- stats2
__global__ void stats2(const float* __restrict__ pcol,
                       const float* __restrict__ ptot,
                       float* __restrict__ scale) {
    const int b = blockIdx.x, t = threadIdx.x;   // 64 threads
    float c = 0.f;
    #pragma unroll
    for (int p = 0; p < 32; ++p) c += pcol[(b * 32 + p) * 64 + t];
    float s2 = c * c;
    #pragma unroll
    for (int off = 32; off > 0; off >>= 1) s2 += __shfl_down(s2, off);
    if (t == 0) {
        float T = 0.f;
        #pragma unroll
        for (int p = 0; p < 32; ++p) T += ptot[b * 32 + p];
        float cmean = 2.0f * T / (float)NN
                    - 2.0f * s2 / ((float)NN * (float)NN) + 1e-8f;
        scale[b] = -1.0f / (cmean * EPS);
    }
}

// ---------------------------------------------------------------- build_K
// SYMMETRIC: one block per unordered tile pair (I<=J) per batch (528*8 blocks).
// X rows for I- and J-ranges staged in LDS with coalesced loads (fixes the
// 32-row scattered fragment gathers); the SAME 17.4 KB LDS is reused for the
// f32 tile T afterwards (fragments live in registers across the overwrite).
// Emits rsum row-sums + col-sums for the free u1 (v=1) pass.
__global__ __launch_bounds__(256) void build_K(const unsigned short* __restrict__ Xbf,
                                               const float* __restrict__ sq,
                                               const float* __restrict__ scale,
                                               unsigned char* __restrict__ K,
                                               float* __restrict__ rsum) {
    __shared__ __align__(16) unsigned char SMEM[64 * 68 * 4];   // 17408 B
    unsigned short (*Xs)[64][68] = (unsigned short (*)[64][68])SMEM;  // [2][64][68]
    float (*T)[68] = (float (*)[68])SMEM;                              // [64][68]
    const int bid = blockIdx.x;                   // 0..4223
    const int b = bid & 7;
    int q = bid >> 3, I = 0;                      // triangular decode (uniform)
    while (q >= 32 - I) { q -= 32 - I; ++I; }
    const int J = I + q;                          // I <= J
    const int t = threadIdx.x, w = t >> 6;
    const int lane = t & 63, l31 = lane & 31, lh = lane >> 5;
    const int wr = w >> 1, wc = w & 1;            // 32x32 quadrant of 64x64 tile
    const unsigned short* Xb = Xbf + (size_t)b * NN * DD;
    // ---- stage X rows (I-range and J-range) into LDS, coalesced 16B/lane
    {
        const unsigned short* XbI = Xb + (size_t)(I * 64) * DD;
        const unsigned short* XbJ = Xb + (size_t)(J * 64) * DD;
        #pragma unroll
        for (int i = 0; i < 2; ++i) {
            const int f = t + i * 256;            // 0..511
            const int row = f >> 3, c8 = (f & 7) * 8;
            uint4 a = *(const uint4*)(XbI + (size_t)row * DD + c8);
            *(uint2*)&Xs[0][row][c8]     = make_uint2(a.x, a.y);
            *(uint2*)&Xs[0][row][c8 + 4] = make_uint2(a.z, a.w);
            uint4 c = *(const uint4*)(XbJ + (size_t)row * DD + c8);
            *(uint2*)&Xs[1][row][c8]     = make_uint2(c.x, c.y);
            *(uint2*)&Xs[1][row][c8 + 4] = make_uint2(c.z, c.w);
        }
    }
    __syncthreads();
    // ---- fragments from LDS (pitch-68 -> bank stride 2 -> free 2-way)
    bf16x8 af[4], bf[4];
    {
        const int rI = wr * 32 + l31, rJ = wc * 32 + l31;
        #pragma unroll
        for (int s = 0; s < 4; ++s) {             // k = s*16 + lh*8 + (0..7)
            union { uint2 q[2]; bf16x8 v; } ua, ub;
            ua.q[0] = *(const uint2*)&Xs[0][rI][s * 16 + lh * 8];
            ua.q[1] = *(const uint2*)&Xs[0][rI][s * 16 + lh * 8 + 4];
            af[s] = ua.v;
            ub.q[0] = *(const uint2*)&Xs[1][rJ][s * 16 + lh * 8];
            ub.q[1] = *(const uint2*)&Xs[1][rJ][s * 16 + lh * 8 + 4];
            bf[s] = ub.v;
        }
    }
    __syncthreads();                              // all Xs reads done before T
    f32x16 acc = {};
    #pragma unroll
    for (int s = 0; s < 4; ++s)
        acc = __builtin_amdgcn_mfma_f32_32x32x16_bf16(af[s], bf[s], acc, 0, 0, 0);
    // C/D: col = l31, row = (r&3) + 8*(r>>2) + 4*lh   [m74/m101 verified]
    const float sc = scale[b];
    const float* sqb = sq + b * NN;
    const int gm = J * 64 + wc * 32 + l31;
    const float sqm = sqb[gm];
    #pragma unroll
    for (int r = 0; r < 16; ++r) {
        const int row = (r & 3) + 8 * (r >> 2) + 4 * lh;
        const int gn = I * 64 + wr * 32 + row;
        float val = KSCALE * __expf(sc * (sqb[gn] + sqm - 2.0f * acc[r]));
        T[wr * 32 + row][wc * 32 + l31] = (gn == gm) ? 0.0f : val;
    }
    __syncthreads();
    unsigned char* Kb = K + (size_t)b * NN * NN;
    // ---- store 1: K[I-rows][J-cols], row-major from LDS, + row-sums
    {
        const int orow = t >> 2, oseg = t & 3;    // 64 rows x 4 segs of 16
        float vv[16];
        #pragma unroll
        for (int j = 0; j < 4; ++j)
            *(float4*)&vv[j * 4] = *(const float4*)&T[orow][oseg * 16 + j * 4];
        float rs = 0.f;
        #pragma unroll
        for (int j = 0; j < 16; ++j) rs += vv[j];
        rs += __shfl_down(rs, 2);
        rs += __shfl_down(rs, 1);
        if (oseg == 0)
            rsum[((size_t)b * 32 + J) * NN + I * 64 + orow] = rs;
        uint4 o;
        o.x = pack4_e4m3(vv[0],  vv[1],  vv[2],  vv[3]);
        o.y = pack4_e4m3(vv[4],  vv[5],  vv[6],  vv[7]);
        o.z = pack4_e4m3(vv[8],  vv[9],  vv[10], vv[11]);
        o.w = pack4_e4m3(vv[12], vv[13], vv[14], vv[15]);
        *(uint4*)(Kb + (size_t)(I * 64 + orow) * NN + J * 64 + oseg * 16) = o;
    }
    // ---- store 2 (I<J only): transpose tile -> K[J-rows][I-cols], + col-sums
    if (I != J) {
        const int c = t >> 2, rseg = t & 3;       // 64 cols x 4 segs of 16 rows
        float vv[16];
        #pragma unroll
        for (int j = 0; j < 16; ++j) vv[j] = T[rseg * 16 + j][c];
        float csum = 0.f;
        #pragma unroll
        for (int j = 0; j < 16; ++j) csum += vv[j];
        csum += __shfl_down(csum, 2);
        csum += __shfl_down(csum, 1);
        if (rseg == 0)
            rsum[((size_t)b * 32 + I) * NN + J * 64 + c] = csum;
        uint4 o;
        o.x = pack4_e4m3(vv[0],  vv[1],  vv[2],  vv[3]);
        o.y = pack4_e4m3(vv[4],  vv[5],  vv[6],  vv[7]);
        o.z = pack4_e4m3(vv[8],  vv[9],  vv[10], vv[11]);
        o.w = pack4_e4m3(vv[12], vv[13], vv[14], vv[15]);
        *(uint4*)(Kb + (size_t)(J * 64 + c) * NN + I * 64 + rseg * 16) = o;
    }
}

// ---------------------------------------------------------------- ucombine
// u1[b,n] = (w+1e-16) / ( sum_g rsum[b][g][n] + KSCALE )   (v=1 pass, free)
__global__ __launch_bounds__(256) void ucombine(const float* __restrict__ rsum,
                                                const float* __restrict__ W,
                                                float* __restrict__ u) {
    const int idx = blockIdx.x * 256 + threadIdx.x;   // 0..16383
    const int b = idx >> 11, n = idx & (NN - 1);
    float s = 0.f;
    #pragma unroll
    for (int g = 0; g < 32; ++g)
        s += rsum[((size_t)b * 32 + g) * NN + n];
    u[idx] = (W[idx] + 1e-16f) / (s + KSCALE);
}

// ---------------------------------------------------------------- sink_pass
// MODE 0: u[n] = (w[n]+1e-16) / ( sum_m K8[n,m]*v[m] + KSCALE*v[n] )
// MODE 1: v[m] = (1/N)        / ( sum_n K8[m,n]*u[n] + KSCALE*u[m] )
template <int MODE>
__global__ __launch_bounds__(256) void sink_pass(const unsigned char* __restrict__ K,
                                                 const float* __restrict__ vin,
                                                 const float* __restrict__ wts,
                                                 float* __restrict__ out) {
    __shared__ float vs[NN];
    const int bid = blockIdx.x;                   // 0..2047
    const int b = bid & 7, j = bid >> 3;          // j 0..255
    const int t = threadIdx.x, w = t >> 6, lane = t & 63;
    const float* vb = vin + (size_t)b * NN;
    #pragma unroll
    for (int s = 0; s < 2; ++s)
        *(float4*)&vs[(t + s * 256) * 4] = *(const float4*)&vb[(t + s * 256) * 4];
    __syncthreads();
    const int r0 = j * 8 + w * 2;                 // 2 rows per wave
    const unsigned char* Kr0 = K + ((size_t)b * NN + r0) * NN;
    const unsigned char* Kr1 = Kr0 + NN;
    float a0 = 0.f, a1 = 0.f;
    #pragma unroll
    for (int it = 0; it < 2; ++it) {
        const int m0 = it * 1024 + lane * 16;
        const uint4 ka = *(const uint4*)(Kr0 + m0);
        const uint4 kb = *(const uint4*)(Kr1 + m0);
        const float4 v0 = *(const float4*)&vs[m0];
        const float4 v1 = *(const float4*)&vs[m0 + 4];
        const float4 v2 = *(const float4*)&vs[m0 + 8];
        const float4 v3 = *(const float4*)&vs[m0 + 12];
        {
            f32x2 q0 = cvt2_fp8<false>(ka.x), q1 = cvt2_fp8<true>(ka.x);
            f32x2 q2 = cvt2_fp8<false>(ka.y), q3 = cvt2_fp8<true>(ka.y);
            f32x2 q4 = cvt2_fp8<false>(ka.z), q5 = cvt2_fp8<true>(ka.z);
            f32x2 q6 = cvt2_fp8<false>(ka.w), q7 = cvt2_fp8<true>(ka.w);
            a0 += q0[0]*v0.x + q0[1]*v0.y + q1[0]*v0.z + q1[1]*v0.w
                + q2[0]*v1.x + q2[1]*v1.y + q3[0]*v1.z + q3[1]*v1.w
                + q4[0]*v2.x + q4[1]*v2.y + q5[0]*v2.z + q5[1]*v2.w
                + q6[0]*v3.x + q6[1]*v3.y + q7[0]*v3.z + q7[1]*v3.w;
        }
        {
            f32x2 q0 = cvt2_fp8<false>(kb.x), q1 = cvt2_fp8<true>(kb.x);
            f32x2 q2 = cvt2_fp8<false>(kb.y), q3 = cvt2_fp8<true>(kb.y);
            f32x2 q4 = cvt2_fp8<false>(kb.z), q5 = cvt2_fp8<true>(kb.z);
            f32x2 q6 = cvt2_fp8<false>(kb.w), q7 = cvt2_fp8<true>(kb.w);
            a1 += q0[0]*v0.x + q0[1]*v0.y + q1[0]*v0.z + q1[1]*v0.w
                + q2[0]*v1.x + q2[1]*v1.y + q3[0]*v1.z + q3[1]*v1.w
                + q4[0]*v2.x + q4[1]*v2.y + q5[0]*v2.z + q5[1]*v2.w
                + q6[0]*v3.x + q6[1]*v3.y + q7[0]*v3.z + q7[1]*v3.w;
        }
    }
    #pragma unroll
    for (int off = 32; off > 0; off >>= 1) {
        a0 += __shfl_down(a0, off);
        a1 += __shfl_down(a1, off);
    }
    if (lane == 0) {
        const float n0 = (MODE == 0) ? (wts[(size_t)b*NN + r0] + 1e-16f) : (1.0f/(float)NN);
        const float n1 = (MODE == 0) ? (wts[(size_t)b*NN + r0 + 1] + 1e-16f) : (1.0f/(float)NN);
        out[(size_t)b * NN + r0]     = n0 / (a0 + KSCALE * vs[r0]);
        out[(size_t)b * NN + r0 + 1] = n1 / (a1 + KSCALE * vs[r0 + 1]);
    }
}

// ---------------------------------------------------------------- yprep
// Yt[b][d][n] = bf16( u[b][n] * X[b][n][d] )   (transposed for MFMA B-frags)
__global__ __launch_bounds__(256) void yprep(const float* __restrict__ X,
                                             const float* __restrict__ u,
                                             unsigned short* __restrict__ Yt) {
    __shared__ float T[64][65];
    const int bid = blockIdx.x;                   // 0..255
    const int b = bid & 7, nt = bid >> 3;
    const int t = threadIdx.x;
    const int nl = t >> 2, c0 = (t & 3) << 4;
    const float* Xb = X + ((size_t)b * NN + nt * 64) * DD;
    const float uu = u[(size_t)b * NN + nt * 64 + nl];
    #pragma unroll
    for (int j = 0; j < 4; ++j) {
        float4 x = *(const float4*)(Xb + (size_t)nl * DD + c0 + j * 4);
        T[c0 + j * 4 + 0][nl] = uu * x.x;
        T[c0 + j * 4 + 1][nl] = uu * x.y;
        T[c0 + j * 4 + 2][nl] = uu * x.z;
        T[c0 + j * 4 + 3][nl] = uu * x.w;
    }
    __syncthreads();
    const int d = t >> 2, n0 = (t & 3) << 4;
    unsigned short* Yr = Yt + ((size_t)b * DD + d) * NN + nt * 64 + n0;
    unsigned int ow[8];
    #pragma unroll
    for (int j = 0; j < 8; ++j) {
        unsigned int lo = f2bf_rne(T[d][n0 + 2 * j]);
        unsigned int hi = f2bf_rne(T[d][n0 + 2 * j + 1]);
        ow[j] = lo | (hi << 16);
    }
    *(uint4*)(Yr)     = make_uint4(ow[0], ow[1], ow[2], ow[3]);
    *(uint4*)(Yr + 8) = make_uint4(ow[4], ow[5], ow[6], ow[7]);
}

// ---------------------------------------------------------------- out_gemm
// pbuf[nc,b,m,d] = sum_{n in chunk} K8[m,n]*u[n]*x[n,d]  via bf16 MFMA.
// LDS-staged K and Y tiles; dpart side-channel fuses the final v-update.
#define KP 136
#define YP 264
__global__ __launch_bounds__(256) void out_gemm(const unsigned char* __restrict__ K,
                                                const unsigned short* __restrict__ Yt,
                                                const float* __restrict__ u,
                                                float* __restrict__ pbuf,
                                                float* __restrict__ dpart) {
    __shared__ __align__(16) unsigned char KsB[64 * KP];
    __shared__ __align__(16) unsigned char YsB[64 * YP];
    const int bid = blockIdx.x;                   // 0..1023
    const int b = bid & 7, tix = bid >> 3;        // tix 0..127
    const int nc = tix & (NC - 1), mt = tix >> 2; // mt 0..31
    const int t = threadIdx.x, w = t >> 6, lane = t & 63;
    const int l31 = lane & 31, lh = lane >> 5;
    const int wr = w >> 1, wc = w & 1;
    const unsigned char*  Kb = K + (size_t)b * NN * NN + (size_t)(mt * 64) * NN;
    const unsigned short* Yb = Yt + (size_t)b * DD * NN;
    const float* ub = u + (size_t)b * NN;
    f32x16 acc = {};
    float ds = 0.f;
    for (int st = 0; st < (NN / NC) / 128; ++st) {
        const int n0 = nc * (NN / NC) + st * 128;
        __syncthreads();
        #pragma unroll
        for (int i = 0; i < 2; ++i) {             // K tile: 64 rows x 128 B
            const int f = t + i * 256;            // 0..511
            const int row = f >> 3, seg = (f & 7) * 16;
            *(uint4*)(KsB + row * KP + seg) =
                *(const uint4*)(Kb + (size_t)row * NN + n0 + seg);
        }
        #pragma unroll
        for (int i = 0; i < 4; ++i) {             // Y tile: 64 rows x 128 bf16
            const int f = t + i * 256;            // 0..1023
            const int row = f >> 4, sege = (f & 15) * 8;
            *(uint4*)(YsB + row * YP + sege * 2) =
                *(const uint4*)(Yb + (size_t)row * NN + n0 + sege);
        }
        __syncthreads();
        #pragma unroll
        for (int kk = 0; kk < 8; ++kk) {
            const uint2 k8 = *(const uint2*)(KsB + (wr * 32 + l31) * KP
                                             + kk * 16 + lh * 8);
            f32x2 p0 = cvt2_fp8<false>(k8.x);
            f32x2 p1 = cvt2_fp8<true>(k8.x);
            f32x2 p2 = cvt2_fp8<false>(k8.y);
            f32x2 p3 = cvt2_fp8<true>(k8.y);
            if (wc == 0) {
                const int nu = n0 + kk * 16 + lh * 8;
                const float4 ua = *(const float4*)(ub + nu);
                const float4 uc = *(const float4*)(ub + nu + 4);
                ds += p0[0]*ua.x + p0[1]*ua.y + p1[0]*ua.z + p1[1]*ua.w
                    + p2[0]*uc.x + p2[1]*uc.y + p3[0]*uc.z + p3[1]*uc.w;
            }
            union { unsigned int u4[4]; bf16x8 v8; } av;
            av.u4[0] = __builtin_amdgcn_perm(__float_as_uint(p0[1]), __float_as_uint(p0[0]), 0x07060302);
            av.u4[1] = __builtin_amdgcn_perm(__float_as_uint(p1[1]), __float_as_uint(p1[0]), 0x07060302);
            av.u4[2] = __builtin_amdgcn_perm(__float_as_uint(p2[1]), __float_as_uint(p2[0]), 0x07060302);
            av.u4[3] = __builtin_amdgcn_perm(__float_as_uint(p3[1]), __float_as_uint(p3[0]), 0x07060302);
            const unsigned char* yb = YsB + (wc * 32 + l31) * YP
                                    + (kk * 16 + lh * 8) * 2;
            union { uint2 u2[2]; bf16x8 v8; } bv;
            bv.u2[0] = *(const uint2*)(yb);
            bv.u2[1] = *(const uint2*)(yb + 8);
            acc = __builtin_amdgcn_mfma_f32_32x32x16_bf16(av.v8, bv.v8, acc, 0, 0, 0);
        }
    }
    ds += __shfl_down(ds, 32);
    if (wc == 0 && lh == 0)
        dpart[((size_t)nc * BB + b) * NN + mt * 64 + wr * 32 + l31] = ds;
    float* pb = pbuf + (((size_t)nc * BB + b) * NN + mt * 64 + wr * 32) * DD
              + wc * 32 + l31;
    #pragma unroll
    for (int r = 0; r < 16; ++r) {
        const int row = (r & 3) + 8 * (r >> 2) + 4 * lh;
        pb[(size_t)row * DD] = acc[r];
    }
}

// ---------------------------------------------------------------- out_reduce
__global__ __launch_bounds__(256) void out_reduce(const float* __restrict__ pbuf,
                                                  const float* __restrict__ dpart,
                                                  const float* __restrict__ u,
                                                  const float* __restrict__ X,
                                                  float* __restrict__ outP) {
    const int idx = blockIdx.x * 256 + threadIdx.x;   // per float4
    const int d4 = idx & (DD / 4 - 1);
    const int bm = idx >> 4;                           // b*NN + m
    float4 s = make_float4(0.f, 0.f, 0.f, 0.f);
    float denom = 0.f;
    #pragma unroll
    for (int nc = 0; nc < NC; ++nc) {
        float4 p = *(const float4*)(pbuf + (size_t)nc * BB * NN * DD
                                    + (size_t)bm * DD + d4 * 4);
        s.x += p.x; s.y += p.y; s.z += p.z; s.w += p.w;
        denom += dpart[(size_t)nc * BB * NN + bm];
    }
    const float um = KSCALE * u[bm];
    denom += um;
    float4 xx = *(const float4*)(X + (size_t)bm * DD + d4 * 4);
    s.x += um * xx.x; s.y += um * xx.y; s.z += um * xx.z; s.w += um * xx.w;
    const float inv = 1.0f / denom;
    *(float4*)(outP + (size_t)bm * DD + d4 * 4) =
        make_float4(inv * s.x, inv * s.y, inv * s.z, inv * s.w);
}

// ---------------------------------------------------------------- launch
extern "C" void kernel_launch(void* const* d_in, const int* in_sizes, int n_in,
                              void* d_out, int out_size, void* d_ws, size_t ws_size,
                              hipStream_t stream) {
    const float* X = (const float*)d_in[0];   // particles [B,N,D]
    const float* W = (const float*)d_in[1];   // weights   [B,N]
    float* outP = (float*)d_out;                       // [B,N,D]
    float* outW = outP + (size_t)BB * NN * DD;         // [B,N]

    float* ws = (float*)d_ws;
    const size_t nfloats = (size_t)BB * NN          // sq
                         + 16                       // scale
                         + 2 * (size_t)BB * NN      // u, v
                         + (size_t)BB * 32 * 64 + BB * 32   // pcol, ptot
                         + (size_t)NC * BB * NN * DD        // pbuf
                         + (size_t)BB * 32 * NN             // rsum
                         + (size_t)NC * BB * NN;            // dpart
    const size_t need = nfloats * 4
                      + (size_t)BB * NN * DD * 2    // Xbf
                      + (size_t)BB * DD * NN * 2    // Yt
                      + (size_t)BB * NN * NN;       // K fp8
    if (ws_size < need) return;

    float* sq    = ws;
    float* scale = sq + (size_t)BB * NN;
    float* u     = scale + 16;
    float* v     = u + (size_t)BB * NN;
    float* pcol  = v + (size_t)BB * NN;
    float* ptot  = pcol + (size_t)BB * 32 * 64;
    float* pbuf  = ptot + BB * 32;
    float* rsum  = pbuf + (size_t)NC * BB * NN * DD;
    float* dpart = rsum + (size_t)BB * 32 * NN;
    unsigned short* Xbf = (unsigned short*)(dpart + (size_t)NC * BB * NN);
    unsigned short* Yt  = Xbf + (size_t)BB * NN * DD;
    unsigned char*  K   = (unsigned char*)(Yt + (size_t)BB * DD * NN);

    stats1<<<dim3(BB * 32), 256, 0, stream>>>(X, Xbf, sq, pcol, ptot, outW);
    stats2<<<dim3(BB), 64, 0, stream>>>(pcol, ptot, scale);
    build_K<<<dim3(528 * BB), 256, 0, stream>>>(Xbf, sq, scale, K, rsum);
    ucombine<<<dim3(BB * NN / 256), 256, 0, stream>>>(rsum, W, u);   // u1 (v=1)
    for (int i = 0; i < 9; ++i) {
        sink_pass<1><<<dim3(BB * NN / 8), 256, 0, stream>>>(K, u, W, v);  // v_i
        sink_pass<0><<<dim3(BB * NN / 8), 256, 0, stream>>>(K, v, W, u);  // u_{i+1}
    }
    yprep<<<dim3(BB * NN / 64), 256, 0, stream>>>(X, u, Yt);
    out_gemm<<<dim3((NN / 64) * NC * BB), 256, 0, stream>>>(K, Yt, u, pbuf, dpart);
    out_reduce<<<dim3(BB * NN * DD / 4 / 256), 256, 0, stream>>>(pbuf, dpart, u, X, outP);
}

// Round 15
// 151.496 us; speedup vs baseline: 14.3946x; 1.0331x over previous
//
#include <hip/hip_runtime.h>

#define BB 8
#define NN 2048
#define DD 64
#define NC 4            // split-K chunks for out_gemm
constexpr float EPS = 0.1f;
constexpr float KSCALE = 4096.0f;   // off-diag fp8 scale; diag handled analytically

typedef short bf16x8 __attribute__((ext_vector_type(8)));
typedef float f32x16 __attribute__((ext_vector_type(16)));
typedef float f32x2  __attribute__((ext_vector_type(2)));

// ---------------------------------------------------------------- fp8 helpers
__device__ inline float e4m3_to_f32_manual(unsigned int b) {
    unsigned int e = (b >> 3) & 15u, m = b & 7u;
    float v;
    if (e == 0) v = (float)m * 0.001953125f;              // m * 2^-9
    else        v = __uint_as_float(((e + 120u) << 23) | (m << 20));
    return (b & 0x80u) ? -v : v;
}

template <bool HI>
__device__ inline f32x2 cvt2_fp8(unsigned int w) {
#if __has_builtin(__builtin_amdgcn_cvt_pk_f32_fp8)
    return __builtin_amdgcn_cvt_pk_f32_fp8(w, HI);
#else
    f32x2 r; unsigned int s = HI ? (w >> 16) : w;
    r[0] = e4m3_to_f32_manual(s & 255u);
    r[1] = e4m3_to_f32_manual((s >> 8) & 255u);
    return r;
#endif
}

__device__ inline unsigned char f32_to_e4m3(float f) {   // f in [0, 448]
#if __has_builtin(__builtin_amdgcn_cvt_pk_fp8_f32)
    return (unsigned char)(__builtin_amdgcn_cvt_pk_fp8_f32(f, f, 0, false) & 0xFF);
#else
    if (!(f > 0.f)) return 0;
    if (f >= 448.f) return 0x7E;
    int e; float m = frexpf(f, &e);            // f = m*2^e, m in [0.5,1)
    if (e >= -5) {                              // normal: f >= 2^-6
        int mant = (int)roundf(m * 16.f) - 8;   // 0..8
        int ef = e + 6;
        if (mant == 8) { mant = 0; ef += 1; }
        if (ef >= 16) return 0x7E;
        return (unsigned char)((ef << 3) | mant);
    }
    int mant = (int)roundf(f * 512.f);          // subnormal
    if (mant >= 8) return 0x08;
    return (unsigned char)mant;
#endif
}

__device__ inline unsigned int pack4_e4m3(float a, float b, float c, float d) {
#if __has_builtin(__builtin_amdgcn_cvt_pk_fp8_f32)
    unsigned int w = 0;
    w = (unsigned int)__builtin_amdgcn_cvt_pk_fp8_f32(a, b, (int)w, false);
    w = (unsigned int)__builtin_amdgcn_cvt_pk_fp8_f32(c, d, (int)w, true);
    return w;
#else
    return (unsigned int)f32_to_e4m3(a) | ((unsigned int)f32_to_e4m3(b) << 8)
         | ((unsigned int)f32_to_e4m3(c) << 16) | ((unsigned int)f32_to_e4m3(d) << 24);
#endif
}

__device__ inline unsigned short f2bf_rne(float f) {
    unsigned int u = __float_as_uint(f);
    u += 0x7FFFu + ((u >> 16) & 1u);
    return (unsigned short)(u >> 16);
}

// ---------------------------------------------------------------- stats1
// Also initializes outW (folded former init_w launch).
__global__ __launch_bounds__(256) void stats1(const float* __restrict__ X,
                                              unsigned short* __restrict__ Xbf,
                                              float* __restrict__ sq,
                                              float* __restrict__ pcol,
                                              float* __restrict__ ptot,
                                              float* __restrict__ outW) {
    const int blk = blockIdx.x;          // 0 .. BB*32-1
    const int b   = blk & 7;
    const int ch  = blk >> 3;            // 0..31
    const int r0  = ch * 64;
    const int t = threadIdx.x, w = t >> 6, lane = t & 63;
    const int gidx = blk * 256 + t;
    if (gidx < BB * NN) outW[gidx] = 1.0f / (float)NN;
    const float* Xb = X + (size_t)b * NN * DD;
    unsigned short* Xbfb = Xbf + (size_t)b * NN * DD;
    float cs = 0.f, sqtot = 0.f;
    #pragma unroll
    for (int i = w; i < 64; i += 4) {
        const int row = r0 + i;
        float x = Xb[(size_t)row * DD + lane];
        unsigned short hb = f2bf_rne(x);
        Xbfb[(size_t)row * DD + lane] = hb;
        float xr = __uint_as_float((unsigned int)hb << 16);
        cs += xr;
        float s = xr * xr;
        #pragma unroll
        for (int off = 32; off > 0; off >>= 1) s += __shfl_down(s, off);
        if (lane == 0) { sq[b * NN + row] = s; sqtot += s; }
    }
    __shared__ float colS[4][64];
    __shared__ float totS[4];
    colS[w][lane] = cs;
    if (lane == 0) totS[w] = sqtot;
    __syncthreads();
    if (t < 64)
        pcol[(b * 32 + ch) * 64 + t] = colS[0][t] + colS[1][t] + colS[2][t] + colS[3][t];
    if (t == 0)
        ptot[b * 32 + ch] = totS[0] + totS[1] + totS[2] + totS[3];
}

// ---------------------------------------------------------------- stats2
__global__ void stats2(const float* __restrict__ pcol,
                       const float* __restrict__ ptot,
                       float* __restrict__ scale) {
    const int b = blockIdx.x, t = threadIdx.x;   // 64 threads
    float c = 0.f;
    #pragma unroll
    for (int p = 0; p < 32; ++p) c += pcol[(b * 32 + p) * 64 + t];
    float s2 = c * c;
    #pragma unroll
    for (int off = 32; off > 0; off >>= 1) s2 += __shfl_down(s2, off);
    if (t == 0) {
        float T = 0.f;
        #pragma unroll
        for (int p = 0; p < 32; ++p) T += ptot[b * 32 + p];
        float cmean = 2.0f * T / (float)NN
                    - 2.0f * s2 / ((float)NN * (float)NN) + 1e-8f;
        scale[b] = -1.0f / (cmean * EPS);
    }
}

// ---------------------------------------------------------------- build_K
// SYMMETRIC: one block per unordered tile pair (I<=J) per batch (528*8 blocks).
// X rows for I- and J-ranges staged in LDS with coalesced loads; the SAME
// 17.4 KB LDS is reused for the f32 tile T afterwards.
// Emits rsum row-sums + col-sums for the free u1 (v=1) pass.
__global__ __launch_bounds__(256) void build_K(const unsigned short* __restrict__ Xbf,
                                               const float* __restrict__ sq,
                                               const float* __restrict__ scale,
                                               unsigned char* __restrict__ K,
                                               float* __restrict__ rsum) {
    __shared__ __align__(16) unsigned char SMEM[64 * 68 * 4];   // 17408 B
    unsigned short (*Xs)[64][68] = (unsigned short (*)[64][68])SMEM;  // [2][64][68]
    float (*T)[68] = (float (*)[68])SMEM;                              // [64][68]
    const int bid = blockIdx.x;                   // 0..4223
    const int b = bid & 7;
    int q = bid >> 3, I = 0;                      // triangular decode (uniform)
    while (q >= 32 - I) { q -= 32 - I; ++I; }
    const int J = I + q;                          // I <= J
    const int t = threadIdx.x, w = t >> 6;
    const int lane = t & 63, l31 = lane & 31, lh = lane >> 5;
    const int wr = w >> 1, wc = w & 1;            // 32x32 quadrant of 64x64 tile
    const unsigned short* Xb = Xbf + (size_t)b * NN * DD;
    // ---- stage X rows (I-range and J-range) into LDS, coalesced 16B/lane
    {
        const unsigned short* XbI = Xb + (size_t)(I * 64) * DD;
        const unsigned short* XbJ = Xb + (size_t)(J * 64) * DD;
        #pragma unroll
        for (int i = 0; i < 2; ++i) {
            const int f = t + i * 256;            // 0..511
            const int row = f >> 3, c8 = (f & 7) * 8;
            uint4 a = *(const uint4*)(XbI + (size_t)row * DD + c8);
            *(uint2*)&Xs[0][row][c8]     = make_uint2(a.x, a.y);
            *(uint2*)&Xs[0][row][c8 + 4] = make_uint2(a.z, a.w);
            uint4 c = *(const uint4*)(XbJ + (size_t)row * DD + c8);
            *(uint2*)&Xs[1][row][c8]     = make_uint2(c.x, c.y);
            *(uint2*)&Xs[1][row][c8 + 4] = make_uint2(c.z, c.w);
        }
    }
    __syncthreads();
    // ---- fragments from LDS (pitch-68 -> bank stride 2 -> free 2-way)
    bf16x8 af[4], bf[4];
    {
        const int rI = wr * 32 + l31, rJ = wc * 32 + l31;
        #pragma unroll
        for (int s = 0; s < 4; ++s) {             // k = s*16 + lh*8 + (0..7)
            union { uint2 q[2]; bf16x8 v; } ua, ub;
            ua.q[0] = *(const uint2*)&Xs[0][rI][s * 16 + lh * 8];
            ua.q[1] = *(const uint2*)&Xs[0][rI][s * 16 + lh * 8 + 4];
            af[s] = ua.v;
            ub.q[0] = *(const uint2*)&Xs[1][rJ][s * 16 + lh * 8];
            ub.q[1] = *(const uint2*)&Xs[1][rJ][s * 16 + lh * 8 + 4];
            bf[s] = ub.v;
        }
    }
    __syncthreads();                              // all Xs reads done before T
    f32x16 acc = {};
    #pragma unroll
    for (int s = 0; s < 4; ++s)
        acc = __builtin_amdgcn_mfma_f32_32x32x16_bf16(af[s], bf[s], acc, 0, 0, 0);
    // C/D: col = l31, row = (r&3) + 8*(r>>2) + 4*lh   [m74/m101 verified]
    const float sc = scale[b];
    const float* sqb = sq + b * NN;
    const int gm = J * 64 + wc * 32 + l31;
    const float sqm = sqb[gm];
    #pragma unroll
    for (int r = 0; r < 16; ++r) {
        const int row = (r & 3) + 8 * (r >> 2) + 4 * lh;
        const int gn = I * 64 + wr * 32 + row;
        float val = KSCALE * __expf(sc * (sqb[gn] + sqm - 2.0f * acc[r]));
        T[wr * 32 + row][wc * 32 + l31] = (gn == gm) ? 0.0f : val;
    }
    __syncthreads();
    unsigned char* Kb = K + (size_t)b * NN * NN;
    // ---- store 1: K[I-rows][J-cols], row-major from LDS, + row-sums
    {
        const int orow = t >> 2, oseg = t & 3;    // 64 rows x 4 segs of 16
        float vv[16];
        #pragma unroll
        for (int j = 0; j < 4; ++j)
            *(float4*)&vv[j * 4] = *(const float4*)&T[orow][oseg * 16 + j * 4];
        float rs = 0.f;
        #pragma unroll
        for (int j = 0; j < 16; ++j) rs += vv[j];
        rs += __shfl_down(rs, 2);
        rs += __shfl_down(rs, 1);
        if (oseg == 0)
            rsum[((size_t)b * 32 + J) * NN + I * 64 + orow] = rs;
        uint4 o;
        o.x = pack4_e4m3(vv[0],  vv[1],  vv[2],  vv[3]);
        o.y = pack4_e4m3(vv[4],  vv[5],  vv[6],  vv[7]);
        o.z = pack4_e4m3(vv[8],  vv[9],  vv[10], vv[11]);
        o.w = pack4_e4m3(vv[12], vv[13], vv[14], vv[15]);
        *(uint4*)(Kb + (size_t)(I * 64 + orow) * NN + J * 64 + oseg * 16) = o;
    }
    // ---- store 2 (I<J only): transpose tile -> K[J-rows][I-cols], + col-sums
    if (I != J) {
        const int c = t >> 2, rseg = t & 3;       // 64 cols x 4 segs of 16 rows
        float vv[16];
        #pragma unroll
        for (int j = 0; j < 16; ++j) vv[j] = T[rseg * 16 + j][c];
        float csum = 0.f;
        #pragma unroll
        for (int j = 0; j < 16; ++j) csum += vv[j];
        csum += __shfl_down(csum, 2);
        csum += __shfl_down(csum, 1);
        if (rseg == 0)
            rsum[((size_t)b * 32 + I) * NN + J * 64 + c] = csum;
        uint4 o;
        o.x = pack4_e4m3(vv[0],  vv[1],  vv[2],  vv[3]);
        o.y = pack4_e4m3(vv[4],  vv[5],  vv[6],  vv[7]);
        o.z = pack4_e4m3(vv[8],  vv[9],  vv[10], vv[11]);
        o.w = pack4_e4m3(vv[12], vv[13], vv[14], vv[15]);
        *(uint4*)(Kb + (size_t)(J * 64 + c) * NN + I * 64 + rseg * 16) = o;
    }
}

// ---------------------------------------------------------------- ucombine
// u1[b,n] = (w+1e-16) / ( sum_g rsum[b][g][n] + KSCALE )   (v=1 pass, free)
__global__ __launch_bounds__(256) void ucombine(const float* __restrict__ rsum,
                                                const float* __restrict__ W,
                                                float* __restrict__ u) {
    const int idx = blockIdx.x * 256 + threadIdx.x;   // 0..16383
    const int b = idx >> 11, n = idx & (NN - 1);
    float s = 0.f;
    #pragma unroll
    for (int g = 0; g < 32; ++g)
        s += rsum[((size_t)b * 32 + g) * NN + n];
    u[idx] = (W[idx] + 1e-16f) / (s + KSCALE);
}

// ---------------------------------------------------------------- sink_pass
// MODE 0: u[n] = (w[n]+1e-16) / ( sum_m K8[n,m]*v[m] + KSCALE*v[n] )
// MODE 1: v[m] = (1/N)        / ( sum_n K8[m,n]*u[n] + KSCALE*u[m] )
// 16 rows/block (4/wave): v-staging amortized over 16 rows, 4 independent
// K-row streams per wave (deeper MLP), 1024 blocks = 4/CU exactly.
template <int MODE>
__global__ __launch_bounds__(256) void sink_pass(const unsigned char* __restrict__ K,
                                                 const float* __restrict__ vin,
                                                 const float* __restrict__ wts,
                                                 float* __restrict__ out) {
    __shared__ float vs[NN];
    const int bid = blockIdx.x;                   // 0..1023
    const int b = bid & 7, j = bid >> 3;          // j 0..127
    const int t = threadIdx.x, w = t >> 6, lane = t & 63;
    const float* vb = vin + (size_t)b * NN;
    #pragma unroll
    for (int s = 0; s < 2; ++s)
        *(float4*)&vs[(t + s * 256) * 4] = *(const float4*)&vb[(t + s * 256) * 4];
    __syncthreads();
    const int r0 = j * 16 + w * 4;                // 4 rows per wave
    const unsigned char* Kr = K + ((size_t)b * NN + r0) * NN;
    float a[4] = {0.f, 0.f, 0.f, 0.f};
    #pragma unroll
    for (int it = 0; it < 2; ++it) {
        const int m0 = it * 1024 + lane * 16;
        uint4 kv[4];
        #pragma unroll
        for (int r = 0; r < 4; ++r)
            kv[r] = *(const uint4*)(Kr + (size_t)r * NN + m0);
        const float4 v0 = *(const float4*)&vs[m0];
        const float4 v1 = *(const float4*)&vs[m0 + 4];
        const float4 v2 = *(const float4*)&vs[m0 + 8];
        const float4 v3 = *(const float4*)&vs[m0 + 12];
        #pragma unroll
        for (int r = 0; r < 4; ++r) {
            f32x2 q0 = cvt2_fp8<false>(kv[r].x), q1 = cvt2_fp8<true>(kv[r].x);
            f32x2 q2 = cvt2_fp8<false>(kv[r].y), q3 = cvt2_fp8<true>(kv[r].y);
            f32x2 q4 = cvt2_fp8<false>(kv[r].z), q5 = cvt2_fp8<true>(kv[r].z);
            f32x2 q6 = cvt2_fp8<false>(kv[r].w), q7 = cvt2_fp8<true>(kv[r].w);
            a[r] += q0[0]*v0.x + q0[1]*v0.y + q1[0]*v0.z + q1[1]*v0.w
                  + q2[0]*v1.x + q2[1]*v1.y + q3[0]*v1.z + q3[1]*v1.w
                  + q4[0]*v2.x + q4[1]*v2.y + q5[0]*v2.z + q5[1]*v2.w
                  + q6[0]*v3.x + q6[1]*v3.y + q7[0]*v3.z + q7[1]*v3.w;
        }
    }
    #pragma unroll
    for (int off = 32; off > 0; off >>= 1)
        #pragma unroll
        for (int r = 0; r < 4; ++r) a[r] += __shfl_down(a[r], off);
    if (lane == 0) {
        #pragma unroll
        for (int r = 0; r < 4; ++r) {
            const float num = (MODE == 0) ? (wts[(size_t)b * NN + r0 + r] + 1e-16f)
                                          : (1.0f / (float)NN);
            out[(size_t)b * NN + r0 + r] = num / (a[r] + KSCALE * vs[r0 + r]);
        }
    }
}

// ---------------------------------------------------------------- yprep
// Yt[b][d][n] = bf16( u[b][n] * X[b][n][d] )   (transposed for MFMA B-frags)
__global__ __launch_bounds__(256) void yprep(const float* __restrict__ X,
                                             const float* __restrict__ u,
                                             unsigned short* __restrict__ Yt) {
    __shared__ float T[64][65];
    const int bid = blockIdx.x;                   // 0..255
    const int b = bid & 7, nt = bid >> 3;
    const int t = threadIdx.x;
    const int nl = t >> 2, c0 = (t & 3) << 4;
    const float* Xb = X + ((size_t)b * NN + nt * 64) * DD;
    const float uu = u[(size_t)b * NN + nt * 64 + nl];
    #pragma unroll
    for (int j = 0; j < 4; ++j) {
        float4 x = *(const float4*)(Xb + (size_t)nl * DD + c0 + j * 4);
        T[c0 + j * 4 + 0][nl] = uu * x.x;
        T[c0 + j * 4 + 1][nl] = uu * x.y;
        T[c0 + j * 4 + 2][nl] = uu * x.z;
        T[c0 + j * 4 + 3][nl] = uu * x.w;
    }
    __syncthreads();
    const int d = t >> 2, n0 = (t & 3) << 4;
    unsigned short* Yr = Yt + ((size_t)b * DD + d) * NN + nt * 64 + n0;
    unsigned int ow[8];
    #pragma unroll
    for (int j = 0; j < 8; ++j) {
        unsigned int lo = f2bf_rne(T[d][n0 + 2 * j]);
        unsigned int hi = f2bf_rne(T[d][n0 + 2 * j + 1]);
        ow[j] = lo | (hi << 16);
    }
    *(uint4*)(Yr)     = make_uint4(ow[0], ow[1], ow[2], ow[3]);
    *(uint4*)(Yr + 8) = make_uint4(ow[4], ow[5], ow[6], ow[7]);
}

// ---------------------------------------------------------------- out_gemm
// pbuf[nc,b,m,d] = sum_{n in chunk} K8[m,n]*u[n]*x[n,d]  via bf16 MFMA.
// LDS-staged K and Y tiles; dpart side-channel fuses the final v-update.
#define KP 136
#define YP 264
__global__ __launch_bounds__(256) void out_gemm(const unsigned char* __restrict__ K,
                                                const unsigned short* __restrict__ Yt,
                                                const float* __restrict__ u,
                                                float* __restrict__ pbuf,
                                                float* __restrict__ dpart) {
    __shared__ __align__(16) unsigned char KsB[64 * KP];
    __shared__ __align__(16) unsigned char YsB[64 * YP];
    const int bid = blockIdx.x;                   // 0..1023
    const int b = bid & 7, tix = bid >> 3;        // tix 0..127
    const int nc = tix & (NC - 1), mt = tix >> 2; // mt 0..31
    const int t = threadIdx.x, w = t >> 6, lane = t & 63;
    const int l31 = lane & 31, lh = lane >> 5;
    const int wr = w >> 1, wc = w & 1;
    const unsigned char*  Kb = K + (size_t)b * NN * NN + (size_t)(mt * 64) * NN;
    const unsigned short* Yb = Yt + (size_t)b * DD * NN;
    const float* ub = u + (size_t)b * NN;
    f32x16 acc = {};
    float ds = 0.f;
    for (int st = 0; st < (NN / NC) / 128; ++st) {
        const int n0 = nc * (NN / NC) + st * 128;
        __syncthreads();
        #pragma unroll
        for (int i = 0; i < 2; ++i) {             // K tile: 64 rows x 128 B
            const int f = t + i * 256;            // 0..511
            const int row = f >> 3, seg = (f & 7) * 16;
            *(uint4*)(KsB + row * KP + seg) =
                *(const uint4*)(Kb + (size_t)row * NN + n0 + seg);
        }
        #pragma unroll
        for (int i = 0; i < 4; ++i) {             // Y tile: 64 rows x 128 bf16
            const int f = t + i * 256;            // 0..1023
            const int row = f >> 4, sege = (f & 15) * 8;
            *(uint4*)(YsB + row * YP + sege * 2) =
                *(const uint4*)(Yb + (size_t)row * NN + n0 + sege);
        }
        __syncthreads();
        #pragma unroll
        for (int kk = 0; kk < 8; ++kk) {
            const uint2 k8 = *(const uint2*)(KsB + (wr * 32 + l31) * KP
                                             + kk * 16 + lh * 8);
            f32x2 p0 = cvt2_fp8<false>(k8.x);
            f32x2 p1 = cvt2_fp8<true>(k8.x);
            f32x2 p2 = cvt2_fp8<false>(k8.y);
            f32x2 p3 = cvt2_fp8<true>(k8.y);
            if (wc == 0) {
                const int nu = n0 + kk * 16 + lh * 8;
                const float4 ua = *(const float4*)(ub + nu);
                const float4 uc = *(const float4*)(ub + nu + 4);
                ds += p0[0]*ua.x + p0[1]*ua.y + p1[0]*ua.z + p1[1]*ua.w
                    + p2[0]*uc.x + p2[1]*uc.y + p3[0]*uc.z + p3[1]*uc.w;
            }
            union { unsigned int u4[4]; bf16x8 v8; } av;
            av.u4[0] = __builtin_amdgcn_perm(__float_as_uint(p0[1]), __float_as_uint(p0[0]), 0x07060302);
            av.u4[1] = __builtin_amdgcn_perm(__float_as_uint(p1[1]), __float_as_uint(p1[0]), 0x07060302);
            av.u4[2] = __builtin_amdgcn_perm(__float_as_uint(p2[1]), __float_as_uint(p2[0]), 0x07060302);
            av.u4[3] = __builtin_amdgcn_perm(__float_as_uint(p3[1]), __float_as_uint(p3[0]), 0x07060302);
            const unsigned char* yb = YsB + (wc * 32 + l31) * YP
                                    + (kk * 16 + lh * 8) * 2;
            union { uint2 u2[2]; bf16x8 v8; } bv;
            bv.u2[0] = *(const uint2*)(yb);
            bv.u2[1] = *(const uint2*)(yb + 8);
            acc = __builtin_amdgcn_mfma_f32_32x32x16_bf16(av.v8, bv.v8, acc, 0, 0, 0);
        }
    }
    ds += __shfl_down(ds, 32);
    if (wc == 0 && lh == 0)
        dpart[((size_t)nc * BB + b) * NN + mt * 64 + wr * 32 + l31] = ds;
    float* pb = pbuf + (((size_t)nc * BB + b) * NN + mt * 64 + wr * 32) * DD
              + wc * 32 + l31;
    #pragma unroll
    for (int r = 0; r < 16; ++r) {
        const int row = (r & 3) + 8 * (r >> 2) + 4 * lh;
        pb[(size_t)row * DD] = acc[r];
    }
}

// ---------------------------------------------------------------- out_reduce
__global__ __launch_bounds__(256) void out_reduce(const float* __restrict__ pbuf,
                                                  const float* __restrict__ dpart,
                                                  const float* __restrict__ u,
                                                  const float* __restrict__ X,
                                                  float* __restrict__ outP) {
    const int idx = blockIdx.x * 256 + threadIdx.x;   // per float4
    const int d4 = idx & (DD / 4 - 1);
    const int bm = idx >> 4;                           // b*NN + m
    float4 s = make_float4(0.f, 0.f, 0.f, 0.f);
    float denom = 0.f;
    #pragma unroll
    for (int nc = 0; nc < NC; ++nc) {
        float4 p = *(const float4*)(pbuf + (size_t)nc * BB * NN * DD
                                    + (size_t)bm * DD + d4 * 4);
        s.x += p.x; s.y += p.y; s.z += p.z; s.w += p.w;
        denom += dpart[(size_t)nc * BB * NN + bm];
    }
    const float um = KSCALE * u[bm];
    denom += um;
    float4 xx = *(const float4*)(X + (size_t)bm * DD + d4 * 4);
    s.x += um * xx.x; s.y += um * xx.y; s.z += um * xx.z; s.w += um * xx.w;
    const float inv = 1.0f / denom;
    *(float4*)(outP + (size_t)bm * DD + d4 * 4) =
        make_float4(inv * s.x, inv * s.y, inv * s.z, inv * s.w);
}

// ---------------------------------------------------------------- launch
extern "C" void kernel_launch(void* const* d_in, const int* in_sizes, int n_in,
                              void* d_out, int out_size, void* d_ws, size_t ws_size,
                              hipStream_t stream) {
    const float* X = (const float*)d_in[0];   // particles [B,N,D]
    const float* W = (const float*)d_in[1];   // weights   [B,N]
    float* outP = (float*)d_out;                       // [B,N,D]
    float* outW = outP + (size_t)BB * NN * DD;         // [B,N]

    float* ws = (float*)d_ws;
    const size_t nfloats = (size_t)BB * NN          // sq
                         + 16                       // scale
                         + 2 * (size_t)BB * NN      // u, v
                         + (size_t)BB * 32 * 64 + BB * 32   // pcol, ptot
                         + (size_t)NC * BB * NN * DD        // pbuf
                         + (size_t)BB * 32 * NN             // rsum
                         + (size_t)NC * BB * NN;            // dpart
    const size_t need = nfloats * 4
                      + (size_t)BB * NN * DD * 2    // Xbf
                      + (size_t)BB * DD * NN * 2    // Yt
                      + (size_t)BB * NN * NN;       // K fp8
    if (ws_size < need) return;

    float* sq    = ws;
    float* scale = sq + (size_t)BB * NN;
    float* u     = scale + 16;
    float* v     = u + (size_t)BB * NN;
    float* pcol  = v + (size_t)BB * NN;
    float* ptot  = pcol + (size_t)BB * 32 * 64;
    float* pbuf  = ptot + BB * 32;
    float* rsum  = pbuf + (size_t)NC * BB * NN * DD;
    float* dpart = rsum + (size_t)BB * 32 * NN;
    unsigned short* Xbf = (unsigned short*)(dpart + (size_t)NC * BB * NN);
    unsigned short* Yt  = Xbf + (size_t)BB * NN * DD;
    unsigned char*  K   = (unsigned char*)(Yt + (size_t)BB * DD * NN);

    stats1<<<dim3(BB * 32), 256, 0, stream>>>(X, Xbf, sq, pcol, ptot, outW);
    stats2<<<dim3(BB), 64, 0, stream>>>(pcol, ptot, scale);
    build_K<<<dim3(528 * BB), 256, 0, stream>>>(Xbf, sq, scale, K, rsum);
    ucombine<<<dim3(BB * NN / 256), 256, 0, stream>>>(rsum, W, u);   // u1 (v=1)
    for (int i = 0; i < 9; ++i) {
        sink_pass<1><<<dim3(BB * NN / 16), 256, 0, stream>>>(K, u, W, v);  // v_i
        sink_pass<0><<<dim3(BB * NN / 16), 256, 0, stream>>>(K, v, W, u);  // u_{i+1}
    }
    yprep<<<dim3(BB * NN / 64), 256, 0, stream>>>(X, u, Yt);
    out_gemm<<<dim3((NN / 64) * NC * BB), 256, 0, stream>>>(K, Yt, u, pbuf, dpart);
    out_reduce<<<dim3(BB * NN * DD / 4 / 256), 256, 0, stream>>>(pbuf, dpart, u, X, outP);
}